// Round 17
// baseline (1743.153 us; speedup 1.0000x reference)
//
#include <hip/hip_runtime.h>
#include <cstddef>

namespace {

constexpr int B  = 4;
constexpr int C  = 768;
constexpr int T  = 512;
constexpr int H  = 12;
constexpr int D  = 64;
constexpr int NL = 6;
constexpr int W  = 4;
constexpr int FF = 3072;

typedef __attribute__((ext_vector_type(8))) short sh8;
typedef __attribute__((ext_vector_type(4))) float f32x4;

__device__ inline float gelu_exact(float x) {
  return 0.5f * x * (1.0f + erff(x * 0.70710678118654752440f));
}
__device__ inline unsigned short f2b(float f) {
  unsigned u = __float_as_uint(f);
  unsigned r = (u + 0x7fffu + ((u >> 16) & 1u)) >> 16;
  return (unsigned short)r;
}
__device__ inline float b2f(unsigned short u) {
  return __uint_as_float((unsigned)u << 16);
}
__device__ inline void gload_lds16(const void* g, void* l) {
  __builtin_amdgcn_global_load_lds(
      (const __attribute__((address_space(1))) unsigned int*)g,
      (__attribute__((address_space(3))) unsigned int*)l, 16, 0, 0);
}

// ---------------------------------------------------------------------------
// Layer-0 input: x [B][C][T] fp32 c-major -> bf16 t-major + fp32 t-major
__global__ __launch_bounds__(256) void transpose_cvt_in(
    const float* __restrict__ s, unsigned short* __restrict__ dh,
    float* __restrict__ df)
{
  __shared__ float tile[32][33];
  const int b = blockIdx.z;
  const int c0 = blockIdx.y * 32, t0 = blockIdx.x * 32;
  const int tx = threadIdx.x & 31, ty = threadIdx.x >> 5;
  const float* sp = s + ((size_t)b * C + c0) * T + t0;
#pragma unroll
  for (int i = 0; i < 4; ++i)
    tile[ty + i * 8][tx] = sp[(size_t)(ty + i * 8) * T + tx];
  __syncthreads();
  unsigned short* dph = dh + ((size_t)b * T + t0) * C + c0;
  float* dpf = df + ((size_t)b * T + t0) * C + c0;
#pragma unroll
  for (int i = 0; i < 4; ++i) {
    const float v = tile[tx][ty + i * 8];
    dph[(size_t)(ty + i * 8) * C + tx] = f2b(v);
    dpf[(size_t)(ty + i * 8) * C + tx] = v;
  }
}

// Final residual: fp32 t-major [B][T][C] -> fp32 c-major [B][C][T]
__global__ __launch_bounds__(256) void transpose_out(
    const float* __restrict__ s, float* __restrict__ d)
{
  __shared__ float tile[32][33];
  const int b = blockIdx.z;
  const int c0 = blockIdx.y * 32, t0 = blockIdx.x * 32;
  const int tx = threadIdx.x & 31, ty = threadIdx.x >> 5;
  const float* sp = s + ((size_t)b * T + t0) * C + c0;
#pragma unroll
  for (int i = 0; i < 4; ++i)
    tile[ty + i * 8][tx] = sp[(size_t)(ty + i * 8) * C + tx];
  __syncthreads();
  float* dp = d + ((size_t)b * C + c0) * T + t0;
#pragma unroll
  for (int i = 0; i < 4; ++i)
    dp[(size_t)(ty + i * 8) * T + tx] = tile[tx][ty + i * 8];
}

// ---------------------------------------------------------------------------
// QKVO weights fp32 [C][C] -> bf16 fragment-tiled. LDS-staged; nontemporal.
__global__ __launch_bounds__(256) void cvt_qkvo_tiled(
    const float* __restrict__ q, const float* __restrict__ k,
    const float* __restrict__ v, const float* __restrict__ o,
    unsigned short* __restrict__ dq, unsigned short* __restrict__ dk,
    unsigned short* __restrict__ dv, unsigned short* __restrict__ dov)
{
  __shared__ float lds[16][132];
  const int z = blockIdx.y;
  const size_t loff = (size_t)blockIdx.z * C * C;
  const float* s = (z == 0 ? q : z == 1 ? k : z == 2 ? v : o) + loff;
  unsigned short* d = (z == 0 ? dq : z == 1 ? dk : z == 2 ? dv : dov) + loff;
  constexpr int KST = C / 32;
  constexpr int KSG = KST / 4;
  const int mt = blockIdx.x / KSG;
  const int ksg = blockIdx.x % KSG;
  const int tid = threadIdx.x;
#pragma unroll
  for (int p = 0; p < 2; ++p) {
    const int f = tid + p * 256;
    const int row = f >> 5, c4 = f & 31;
    f32x4 vv = __builtin_nontemporal_load(
        (const f32x4*)(s + (size_t)(mt * 16 + row) * C + ksg * 128 + c4 * 4));
    *(f32x4*)&lds[row][c4 * 4] = vv;
  }
  __syncthreads();
  const int ksl = tid >> 6, lane = tid & 63;
  const int l15 = lane & 15, lhi = lane >> 4;
  float4 a = *(const float4*)&lds[l15][ksl * 32 + lhi * 8];
  float4 b = *(const float4*)&lds[l15][ksl * 32 + lhi * 8 + 4];
  sh8 u;
  u[0] = (short)f2b(a.x); u[1] = (short)f2b(a.y);
  u[2] = (short)f2b(a.z); u[3] = (short)f2b(a.w);
  u[4] = (short)f2b(b.x); u[5] = (short)f2b(b.y);
  u[6] = (short)f2b(b.z); u[7] = (short)f2b(b.w);
  *(sh8*)(d + ((size_t)(mt * KST + ksg * 4 + ksl) * 64 + lane) * 8) = u;
}

// FFN weights [O][Ci][3] fp32 -> 3 tap planes fragment-tiled.
__global__ __launch_bounds__(256) void cvt_ffn_tiled(
    const float* __restrict__ s1, const float* __restrict__ s2,
    unsigned short* __restrict__ d1, unsigned short* __restrict__ d2)
{
  __shared__ float lds[16][388];
  const int z = blockIdx.y;
  const int layer = blockIdx.z;
  const float* src = (z ? s2 : s1) + (size_t)layer * FF * C * 3;
  unsigned short* dst = (z ? d2 : d1) + (size_t)layer * 3 * FF * C;
  const int O  = z ? C : FF;
  const int Ci = z ? FF : C;
  const int KST = Ci >> 5;
  const int KSG = KST >> 2;
  const int mt = blockIdx.x / KSG;
  const int ksg = blockIdx.x % KSG;
  const int tid = threadIdx.x;
  const size_t rowlen = (size_t)Ci * 3;
#pragma unroll
  for (int p = 0; p < 6; ++p) {
    const int f = tid + p * 256;
    const int row = f / 96, c4 = f % 96;
    f32x4 vv = __builtin_nontemporal_load(
        (const f32x4*)(src + (size_t)(mt * 16 + row) * rowlen + ksg * 384 + c4 * 4));
    *(f32x4*)&lds[row][c4 * 4] = vv;
  }
  __syncthreads();
  const int ksl = tid >> 6, lane = tid & 63;
  const int l15 = lane & 15, lhi = lane >> 4;
  const int q0 = ksl * 96 + lhi * 24;
  float f[24];
#pragma unroll
  for (int kq = 0; kq < 6; ++kq) {
    float4 t4 = *(const float4*)&lds[l15][q0 + kq * 4];
    f[kq * 4 + 0] = t4.x; f[kq * 4 + 1] = t4.y;
    f[kq * 4 + 2] = t4.z; f[kq * 4 + 3] = t4.w;
  }
  const size_t fragoff = ((size_t)(mt * KST + ksg * 4 + ksl) * 64 + lane) * 8;
#pragma unroll
  for (int tap = 0; tap < 3; ++tap) {
    sh8 u;
#pragma unroll
    for (int j = 0; j < 8; ++j) u[j] = (short)f2b(f[j * 3 + tap]);
    *(sh8*)(dst + (size_t)tap * O * Ci + fragoff) = u;
  }
}

// ---------------------------------------------------------------------------
// 256-thread MFMA conv (BM=128 x BN∈{64,128}).
// A: LDS double-buffered via global_load_lds (fragment-tiled weights).
// B: DIRECT global->VGPR per fragment (16B contiguous), double-buffered in
// registers; no B LDS round-trip (B has zero cross-wave reuse).
// ks-loop unrolled by 2 (all kchunks even) for static reg-buffer indexing.
template <int TAPS, int BN, int KSPLIT, bool GELU, bool MASK_OUT, bool OBF16,
          bool KBIN, bool KBOUT>
__global__ __launch_bounds__(256) void mfma_conv(
    const unsigned short* __restrict__ xin,
    const unsigned short* __restrict__ w0p, const unsigned short* __restrict__ w1p,
    const unsigned short* __restrict__ w2p,
    const float* __restrict__ b0, const float* __restrict__ b1,
    const float* __restrict__ b2,
    const float* __restrict__ mask,
    void* __restrict__ o0p, void* __restrict__ o1p, void* __restrict__ o2p,
    int Cin, int O, int tilesPerPlane, int nz)
{
  constexpr int NF = BN / 32;
  constexpr int NT = T / BN;
  __shared__ unsigned short Aw[2][TAPS * 8 * 512];

  const int nwg = gridDim.x;
  const int orig = blockIdx.x;
  const int wg = (orig & 7) * (nwg >> 3) + (orig >> 3);
  const int txt = wg % NT;
  const int rest = wg / NT;
  const int zz = rest % nz;
  const int ty = rest / nz;

  const int b  = zz / KSPLIT;
  const int kk = zz % KSPLIT;
  const int t0 = txt * BN;
  const int plane = ty / tilesPerPlane;
  const int mt0 = (ty % tilesPerPlane) * 8;
  const int o0 = mt0 * 16;

  const int tid = threadIdx.x;
  const int lane = tid & 63, wid = tid >> 6;
  const int wm = wid >> 1, wn = wid & 1;
  const int l15 = lane & 15, lhi = lane >> 4;
  const int bmask = b * T;

  const unsigned short* wsel = plane == 0 ? w0p : (plane == 1 ? w1p : w2p);
  const float* bp = plane == 0 ? b0 : (plane == 1 ? b1 : b2);

  const int KST = Cin >> 5;
  const int kchunk = KST / KSPLIT;   // even for all instantiations
  const int ks0 = kk * kchunk, ks1 = ks0 + kchunk;
  const int OT = O >> 4;

  const unsigned short* xb_ = xin + (size_t)b * T * Cin;          // t-major
  const unsigned short* xkb = xin + (size_t)b * KST * T * 32;     // K-blocked

  // per-lane B row base (without tap/n): fragment row = trow0 + tap + n*16
  const int trow0 = t0 + wn * (NF * 16) + l15 + ((TAPS == 3) ? -1 : 0);

  auto stageA = [&](int ks, int buf) {
#pragma unroll
    for (int tap = 0; tap < TAPS; ++tap) {
#pragma unroll
      for (int j = 0; j < 2; ++j) {
        const int rt = wid * 2 + j;
        const unsigned short* src =
            wsel + (((size_t)tap * OT + mt0 + rt) * KST + ks) * 512 + lane * 8;
        gload_lds16(src, &Aw[buf][(tap * 8 + rt) * 512]);
      }
    }
  };
  auto loadBall = [&](int ks, sh8* dst) {
#pragma unroll
    for (int tap = 0; tap < TAPS; ++tap)
#pragma unroll
      for (int n = 0; n < NF; ++n) {
        const int tl = trow0 + tap + n * 16;
        sh8 v = (sh8)0;
        if (TAPS == 1 || (unsigned)tl < (unsigned)T) {
          const unsigned short* p = KBIN
              ? xkb + ((size_t)ks * T + tl) * 32 + lhi * 8
              : xb_ + (size_t)tl * Cin + (ks << 5) + lhi * 8;
          v = *(const sh8*)p;
        }
        dst[tap * NF + n] = v;
      }
  };

  f32x4 acc[4][NF] = {};
  sh8 B0[TAPS * NF], B1[TAPS * NF];

  auto compute = [&](int abuf, const sh8* bset) {
#pragma unroll
    for (int tap = 0; tap < TAPS; ++tap) {
      sh8 af[4];
#pragma unroll
      for (int m = 0; m < 4; ++m)
        af[m] = *(const sh8*)&Aw[abuf][(tap * 8 + wm * 4 + m) * 512 + lane * 8];
#pragma unroll
      for (int m = 0; m < 4; ++m)
#pragma unroll
        for (int n = 0; n < NF; ++n)
          acc[m][n] = __builtin_amdgcn_mfma_f32_16x16x32_bf16(
              af[m], bset[tap * NF + n], acc[m][n], 0, 0, 0);
    }
  };

  stageA(ks0, 0);
  loadBall(ks0, B0);
  __syncthreads();   // A buf0 staged (vmcnt drained by syncthreads)

  for (int ks = ks0; ks < ks1; ks += 2) {
    stageA(ks + 1, 1);
    loadBall(ks + 1, B1);
    compute(0, B0);
    __syncthreads();               // buf1 ready; all waves done with buf0
    const bool more2 = (ks + 2 < ks1);
    if (more2) { stageA(ks + 2, 0); loadBall(ks + 2, B0); }
    compute(1, B1);
    __syncthreads();               // buf0 ready; all waves done with buf1
  }

  void* obase = plane == 0 ? o0p : (plane == 1 ? o1p : o2p);
  unsigned short* oph = (unsigned short*)obase + (size_t)b * T * O;
  unsigned short* opk = (unsigned short*)obase + (size_t)b * (O >> 5) * T * 32;
  float* opf = (float*)obase + ((size_t)kk * B + b) * (size_t)T * O;
#pragma unroll
  for (int m = 0; m < 4; ++m) {
    const int o = o0 + (wm * 4 + m) * 16 + (lhi << 2);
#pragma unroll
    for (int n = 0; n < NF; ++n) {
      const int t = t0 + wn * (NF * 16) + n * 16 + l15;
      const float mk = MASK_OUT ? mask[bmask + t] : 1.f;
      float v[4];
#pragma unroll
      for (int r4 = 0; r4 < 4; ++r4) {
        float x = acc[m][n][r4];
        if (KSPLIT > 1) {
          if (kk == 0) x += bp[o + r4];
        } else {
          x += bp[o + r4];
        }
        if (GELU) x = gelu_exact(x);
        if (MASK_OUT) x *= mk;
        v[r4] = x;
      }
      if constexpr (OBF16) {
        ushort4 hz;
        hz.x = f2b(v[0]); hz.y = f2b(v[1]); hz.z = f2b(v[2]); hz.w = f2b(v[3]);
        if constexpr (KBOUT)
          *(ushort4*)(opk + ((size_t)(o >> 5) * T + t) * 32 + (o & 31)) = hz;
        else
          *(ushort4*)(oph + (size_t)t * O + o) = hz;
      } else {
        *(float4*)(opf + (size_t)t * O + o) = make_float4(v[0], v[1], v[2], v[3]);
      }
    }
  }
}

// ---------------------------------------------------------------------------
// Fused attention with 2-phase K/V prefetch. q/k/v t-major bf16 [B][T][C];
// output K-blocked bf16 [B][C/32][T][32]. Ps aliases Qs (dead after prologue).
__global__ __launch_bounds__(256) void fused_attn(
    const unsigned short* __restrict__ qg,
    const unsigned short* __restrict__ kg,
    const unsigned short* __restrict__ vg,
    const float* __restrict__ mask,
    const float* __restrict__ ek,
    const float* __restrict__ ev,
    unsigned short* __restrict__ outp)
{
  constexpr int PITCH = 72;
  __shared__ unsigned short Qs[64 * PITCH];
  __shared__ unsigned short Ks[2][64 * PITCH];
  __shared__ unsigned short Vs[2][64 * PITCH];
  __shared__ float eks[D * 9], evs[D * 9];
  __shared__ float qekl[64 * 12];
  __shared__ float mks[2][64];
  unsigned short* Ps = Qs;

  const int t0 = blockIdx.x * 64;
  const int bh = blockIdx.y;
  const int b = bh / H, h = bh % H;
  const int tid = threadIdx.x;
  const int lane = tid & 63, w = tid >> 6;
  const int l15 = lane & 15, lhi = lane >> 4;

  const size_t base = (size_t)b * T * C + h * D;
  const unsigned short* qh = qg + base;
  const unsigned short* kh = kg + base;
  const unsigned short* vh = vg + base;

  for (int e = tid; e < D * 9; e += 256) { eks[e] = ek[e]; evs[e] = ev[e]; }
  {
    const int tl = tid & 63, d0 = (tid >> 6) << 4;
    const unsigned short* src = qh + (size_t)(t0 + tl) * C + d0;
    *(sh8*)&Qs[tl * PITCH + d0]     = *(const sh8*)(src);
    *(sh8*)&Qs[tl * PITCH + d0 + 8] = *(const sh8*)(src + 8);
  }
  __syncthreads();
  {
    const int tl = tid & 63, g = tid >> 6;
    for (int j = g; j < 9; j += 4) {
      float a = 0.f;
      for (int d = 0; d < D; ++d)
        a = fmaf(b2f(Qs[tl * PITCH + d]), eks[d * 9 + j], a);
      qekl[tl * 12 + j] = a * 0.125f;
    }
  }
  const int t_loc = w * 16 + l15;
  const int t = t0 + t_loc;
  const float mask_t = mask[b * T + t];
  const sh8 bq0 = *(const sh8*)&Qs[t_loc * PITCH + lhi * 8];
  const sh8 bq1 = *(const sh8*)&Qs[t_loc * PITCH + 32 + lhi * 8];

  const int sl = tid & 63, d0s = (tid >> 6) << 4;
  {
    const unsigned short* srck = kh + (size_t)sl * C + d0s;
    *(sh8*)&Ks[0][sl * PITCH + d0s]     = *(const sh8*)(srck);
    *(sh8*)&Ks[0][sl * PITCH + d0s + 8] = *(const sh8*)(srck + 8);
    const unsigned short* srcv = vh + (size_t)sl * C + d0s;
    sh8 u0 = *(const sh8*)(srcv);
    sh8 u1 = *(const sh8*)(srcv + 8);
#pragma unroll
    for (int j = 0; j < 8; ++j) Vs[0][(d0s + j) * PITCH + sl] = (unsigned short)u0[j];
#pragma unroll
    for (int j = 0; j < 8; ++j) Vs[0][(d0s + 8 + j) * PITCH + sl] = (unsigned short)u1[j];
    if (tid < 64) mks[0][tid] = mask[b * T + tid];
  }
  __syncthreads();   // orders all Qs reads before first Ps write

  float m_run = -1e30f, l_run = 0.f;
  f32x4 oacc[4] = {};
  int cur = 0;
  sh8 kr0, kr1, vr0, vr1;
  float mkr = 0.f;

  for (int s0 = 0; s0 < T; s0 += 64) {
    const int nxt = cur ^ 1;
    const bool more = (s0 + 64 < T);
    if (more) {
      const unsigned short* srck = kh + (size_t)(s0 + 64 + sl) * C + d0s;
      kr0 = *(const sh8*)(srck);
      kr1 = *(const sh8*)(srck + 8);
      const unsigned short* srcv = vh + (size_t)(s0 + 64 + sl) * C + d0s;
      vr0 = *(const sh8*)(srcv);
      vr1 = *(const sh8*)(srcv + 8);
      if (tid < 64) mkr = mask[b * T + s0 + 64 + tid];
    }

    float p[16];
#pragma unroll
    for (int n = 0; n < 4; ++n) {
      const sh8 a0 = *(const sh8*)&Ks[cur][(n * 16 + l15) * PITCH + lhi * 8];
      const sh8 a1 = *(const sh8*)&Ks[cur][(n * 16 + l15) * PITCH + 32 + lhi * 8];
      f32x4 acc = {};
      __builtin_amdgcn_s_setprio(1);
      acc = __builtin_amdgcn_mfma_f32_16x16x32_bf16(a0, bq0, acc, 0, 0, 0);
      acc = __builtin_amdgcn_mfma_f32_16x16x32_bf16(a1, bq1, acc, 0, 0, 0);
      __builtin_amdgcn_s_setprio(0);
#pragma unroll
      for (int r = 0; r < 4; ++r) {
        const int s = s0 + n * 16 + lhi * 4 + r;
        float v = acc[r] * 0.125f;
        const int j = s - t + 4;
        if ((unsigned)j < 9u) v += qekl[t_loc * 12 + j];
        if (mask_t * mks[cur][s - s0] == 0.f) v = -10000.0f;
        p[n * 4 + r] = v;
      }
    }
    float mloc = p[0];
#pragma unroll
    for (int i = 1; i < 16; ++i) mloc = fmaxf(mloc, p[i]);
    mloc = fmaxf(mloc, __shfl_xor(mloc, 16));
    mloc = fmaxf(mloc, __shfl_xor(mloc, 32));
    const float m_new = fmaxf(m_run, mloc);
    const float f = __expf(m_run - m_new);
    float sloc = 0.f;
#pragma unroll
    for (int i = 0; i < 16; ++i) { p[i] = __expf(p[i] - m_new); sloc += p[i]; }
    sloc += __shfl_xor(sloc, 16);
    sloc += __shfl_xor(sloc, 32);
    l_run = l_run * f + sloc;
    m_run = m_new;
#pragma unroll
    for (int m = 0; m < 4; ++m)
#pragma unroll
      for (int r = 0; r < 4; ++r) oacc[m][r] *= f;
#pragma unroll
    for (int n = 0; n < 4; ++n) {
      uint2 pk;
      pk.x = (unsigned)f2b(p[n * 4 + 0]) | ((unsigned)f2b(p[n * 4 + 1]) << 16);
      pk.y = (unsigned)f2b(p[n * 4 + 2]) | ((unsigned)f2b(p[n * 4 + 3]) << 16);
      *(uint2*)&Ps[t_loc * PITCH + n * 16 + lhi * 4] = pk;
    }
    asm volatile("s_waitcnt lgkmcnt(0)" ::: "memory");
    const sh8 bp0 = *(const sh8*)&Ps[t_loc * PITCH + lhi * 8];
    const sh8 bp1 = *(const sh8*)&Ps[t_loc * PITCH + 32 + lhi * 8];
    __builtin_amdgcn_s_setprio(1);
#pragma unroll
    for (int m = 0; m < 4; ++m) {
      const sh8 a0 = *(const sh8*)&Vs[cur][(m * 16 + l15) * PITCH + lhi * 8];
      const sh8 a1 = *(const sh8*)&Vs[cur][(m * 16 + l15) * PITCH + 32 + lhi * 8];
      oacc[m] = __builtin_amdgcn_mfma_f32_16x16x32_bf16(a0, bp0, oacc[m], 0, 0, 0);
      oacc[m] = __builtin_amdgcn_mfma_f32_16x16x32_bf16(a1, bp1, oacc[m], 0, 0, 0);
    }
    __builtin_amdgcn_s_setprio(0);
    if (t + 4 >= s0 && t < s0 + 68) {
#pragma unroll
      for (int j = 0; j < 9; ++j) {
        const int s = t + j - 4;
        if (s >= s0 && s < s0 + 64) {
          const float pv = b2f(Ps[t_loc * PITCH + (s - s0)]);
#pragma unroll
          for (int m = 0; m < 4; ++m)
#pragma unroll
            for (int r = 0; r < 4; ++r)
              oacc[m][r] = fmaf(pv, evs[(m * 16 + lhi * 4 + r) * 9 + j], oacc[m][r]);
        }
      }
    }
    if (more) {
      *(sh8*)&Ks[nxt][sl * PITCH + d0s]     = kr0;
      *(sh8*)&Ks[nxt][sl * PITCH + d0s + 8] = kr1;
#pragma unroll
      for (int j = 0; j < 8; ++j) Vs[nxt][(d0s + j) * PITCH + sl] = (unsigned short)vr0[j];
#pragma unroll
      for (int j = 0; j < 8; ++j) Vs[nxt][(d0s + 8 + j) * PITCH + sl] = (unsigned short)vr1[j];
      if (tid < 64) mks[nxt][tid] = mkr;
    }
    __syncthreads();
    cur = nxt;
  }
  const float invl = 1.f / l_run;
  unsigned short* okb = outp + (size_t)b * (C >> 5) * T * 32;
#pragma unroll
  for (int m = 0; m < 4; ++m) {
    ushort4 hz;
    hz.x = f2b(oacc[m][0] * invl);
    hz.y = f2b(oacc[m][1] * invl);
    hz.z = f2b(oacc[m][2] * invl);
    hz.w = f2b(oacc[m][3] * invl);
    const int c = h * D + m * 16 + lhi * 4;
    *(ushort4*)(okb + ((size_t)(c >> 5) * T + t) * 32 + (c & 31)) = hz;
  }
}

// ---------------------------------------------------------------------------
// Wave-per-t add+layernorm, everything t-major.
template <int NP, bool MASKY, bool MASKF>
__global__ __launch_bounds__(256) void add_norm_wave(
    const float* __restrict__ xr, const float* __restrict__ ypart,
    const float* __restrict__ g, const float* __restrict__ bta,
    const float* __restrict__ mask, float* __restrict__ dst,
    unsigned short* __restrict__ dsth)
{
  const int b = blockIdx.y;
  const int t = blockIdx.x * 4 + (threadIdx.x >> 6);
  const int lane = threadIdx.x & 63;
  const float mkt = mask[b * T + t];
  const size_t rowoff = ((size_t)b * T + t) * C;
  const int ci0 = lane * 12;

  float vv[12];
  float sum = 0.f, sq = 0.f;
#pragma unroll
  for (int q = 0; q < 3; ++q) {
    const int ci = ci0 + q * 4;
    float4 xv = *(const float4*)(xr + rowoff + ci);
    float4 yv = make_float4(0.f, 0.f, 0.f, 0.f);
#pragma unroll
    for (int p = 0; p < NP; ++p) {
      float4 t4 = *(const float4*)(ypart + (size_t)p * B * T * C + rowoff + ci);
      yv.x += t4.x; yv.y += t4.y; yv.z += t4.z; yv.w += t4.w;
    }
    if (MASKY) { yv.x *= mkt; yv.y *= mkt; yv.z *= mkt; yv.w *= mkt; }
    const float v0 = xv.x + yv.x, v1 = xv.y + yv.y;
    const float v2 = xv.z + yv.z, v3 = xv.w + yv.w;
    vv[q * 4 + 0] = v0; vv[q * 4 + 1] = v1; vv[q * 4 + 2] = v2; vv[q * 4 + 3] = v3;
    sum += v0 + v1 + v2 + v3;
    sq = fmaf(v0, v0, fmaf(v1, v1, fmaf(v2, v2, fmaf(v3, v3, sq))));
  }
#pragma unroll
  for (int o = 32; o > 0; o >>= 1) {
    sum += __shfl_xor(sum, o);
    sq += __shfl_xor(sq, o);
  }
  const float m = sum * (1.f / C);
  const float rs = rsqrtf(sq * (1.f / C) - m * m + 1e-5f);
#pragma unroll
  for (int q = 0; q < 3; ++q) {
    const int ci = ci0 + q * 4;
    float4 gv = *(const float4*)(g + ci);
    float4 bv = *(const float4*)(bta + ci);
    float o0 = (vv[q * 4 + 0] - m) * rs * gv.x + bv.x;
    float o1 = (vv[q * 4 + 1] - m) * rs * gv.y + bv.y;
    float o2 = (vv[q * 4 + 2] - m) * rs * gv.z + bv.z;
    float o3 = (vv[q * 4 + 3] - m) * rs * gv.w + bv.w;
    if (MASKF) { o0 *= mkt; o1 *= mkt; o2 *= mkt; o3 *= mkt; }
    *(float4*)(dst + rowoff + ci) = make_float4(o0, o1, o2, o3);
    const float hm = MASKF ? 1.f : mkt;
    ushort4 hz;
    hz.x = f2b(o0 * hm); hz.y = f2b(o1 * hm); hz.z = f2b(o2 * hm); hz.w = f2b(o3 * hm);
    *(ushort4*)(dsth + rowoff + ci) = hz;
  }
}

}  // namespace

extern "C" void kernel_launch(void* const* d_in, const int* in_sizes, int n_in,
                              void* d_out, int out_size, void* d_ws, size_t ws_size,
                              hipStream_t stream) {
  const float* x_in = (const float*)d_in[0];
  const float* mask = (const float*)d_in[1];
  const float* Wq = (const float*)d_in[2];
  const float* bq = (const float*)d_in[3];
  const float* Wk = (const float*)d_in[4];
  const float* bk = (const float*)d_in[5];
  const float* Wv = (const float*)d_in[6];
  const float* bv = (const float*)d_in[7];
  const float* Wo = (const float*)d_in[8];
  const float* bo = (const float*)d_in[9];
  const float* ek = (const float*)d_in[10];
  const float* ev = (const float*)d_in[11];
  const float* w1 = (const float*)d_in[12];
  const float* b1 = (const float*)d_in[13];
  const float* w2 = (const float*)d_in[14];
  const float* b2 = (const float*)d_in[15];
  const float* n1g = (const float*)d_in[16];
  const float* n1b = (const float*)d_in[17];
  const float* n2g = (const float*)d_in[18];
  const float* n2b = (const float*)d_in[19];

  float* ws = (float*)d_ws;
  const size_t SZ_X = (size_t)B * C * T;
  const size_t SZ_W1 = (size_t)3 * FF * C;
  float* xr    = ws;
  float* xr1   = xr + SZ_X;
  float* ypart = xr1 + SZ_X;
  unsigned short* xbh = (unsigned short*)(ypart + 4 * SZ_X);
  unsigned short* xfh = xbh + SZ_X;
  unsigned short* qbh = xfh + SZ_X;
  unsigned short* kbh = qbh + SZ_X;
  unsigned short* vbh = kbh + SZ_X;
  unsigned short* hidh = vbh + SZ_X;
  unsigned short* w1t = hidh + (size_t)B * FF * T;
  unsigned short* w2t = w1t + (size_t)NL * SZ_W1;
  unsigned short* wqt = w2t + (size_t)NL * SZ_W1;
  unsigned short* wkt = wqt + (size_t)NL * C * C;
  unsigned short* wvt = wkt + (size_t)NL * C * C;
  unsigned short* wot = wvt + (size_t)NL * C * C;
  float* outp = (float*)d_out;

  const dim3 blk(256);
  transpose_cvt_in<<<dim3(T / 32, C / 32, B), blk, 0, stream>>>(x_in, xbh, xr);
  cvt_qkvo_tiled<<<dim3((C / 16) * (C / 128), 4, NL), blk, 0, stream>>>(
      Wq, Wk, Wv, Wo, wqt, wkt, wvt, wot);
  cvt_ffn_tiled<<<dim3((FF / 16) * (C / 128), 2, NL), blk, 0, stream>>>(
      w1, w2, w1t, w2t);

  for (int i = 0; i < NL; ++i) {
    const size_t wOff = (size_t)i * C * C;
    const unsigned short* w1l = w1t + (size_t)i * SZ_W1;
    const unsigned short* w2l = w2t + (size_t)i * SZ_W1;
    // QKV projection -> bf16 q,k,v t-major   (576 blocks, BN=64)
    mfma_conv<1, 64, 1, false, false, true, false, false>
        <<<dim3(8 * 18 * 4), blk, 0, stream>>>(
        xbh, wqt + wOff, wkt + wOff, wvt + wOff,
        bq + i * C, bk + i * C, bv + i * C, mask,
        qbh, kbh, vbh, C, C, 6, 4);
    // fused attention -> K-blocked bf16
    fused_attn<<<dim3(T / 64, B * H), blk, 0, stream>>>(
        qbh, kbh, vbh, mask, ek + (size_t)i * D * 9, ev + (size_t)i * D * 9, hidh);
    // Wo projection: K-blocked input, split-K3 -> fp32 partials (576 blocks)
    mfma_conv<1, 64, 3, false, false, false, true, false>
        <<<dim3(8 * 6 * 12), blk, 0, stream>>>(
        hidh, wot + wOff, wot + wOff, wot + wOff,
        bo + i * C, bo + i * C, bo + i * C, mask,
        ypart, ypart, ypart, C, C, 6, 12);
    add_norm_wave<3, false, false><<<dim3(T / 4, B), blk, 0, stream>>>(
        xr, ypart, n1g + i * C, n1b + i * C, mask, xr1, xfh);
    // FFN up: t-major in, GELU+mask, K-blocked bf16 out   (384 blocks)
    mfma_conv<3, 128, 1, true, true, true, false, true>
        <<<dim3(4 * 24 * 4), blk, 0, stream>>>(
        xfh, w1l, w1l, w1l, b1 + i * FF, b1 + i * FF, b1 + i * FF, mask,
        hidh, hidh, hidh, C, FF, 24, 4);
    // FFN down: K-blocked in, split-K4 -> fp32 partials   (384 blocks)
    mfma_conv<3, 128, 4, false, false, false, true, false>
        <<<dim3(4 * 6 * 16), blk, 0, stream>>>(
        hidh, w2l, w2l, w2l, b2 + i * C, b2 + i * C, b2 + i * C, mask,
        ypart, ypart, ypart, FF, C, 6, 16);
    add_norm_wave<4, true, true><<<dim3(T / 4, B), blk, 0, stream>>>(
        xr1, ypart, n2g + i * C, n2b + i * C, mask, xr, xbh);
  }
  transpose_out<<<dim3(T / 32, C / 32, B), blk, 0, stream>>>(xr, outp);
}

// Round 18
// 1104.715 us; speedup vs baseline: 1.5779x; 1.5779x over previous
//
#include <hip/hip_runtime.h>
#include <cstddef>

namespace {

constexpr int B  = 4;
constexpr int C  = 768;
constexpr int T  = 512;
constexpr int H  = 12;
constexpr int D  = 64;
constexpr int NL = 6;
constexpr int W  = 4;
constexpr int FF = 3072;

typedef __attribute__((ext_vector_type(8))) short sh8;
typedef __attribute__((ext_vector_type(4))) float f32x4;

__device__ inline float gelu_exact(float x) {
  return 0.5f * x * (1.0f + erff(x * 0.70710678118654752440f));
}
__device__ inline unsigned short f2b(float f) {
  unsigned u = __float_as_uint(f);
  unsigned r = (u + 0x7fffu + ((u >> 16) & 1u)) >> 16;
  return (unsigned short)r;
}
__device__ inline float b2f(unsigned short u) {
  return __uint_as_float((unsigned)u << 16);
}
__device__ inline void gload_lds16(const void* g, void* l) {
  __builtin_amdgcn_global_load_lds(
      (const __attribute__((address_space(1))) unsigned int*)g,
      (__attribute__((address_space(3))) unsigned int*)l, 16, 0, 0);
}

// ---------------------------------------------------------------------------
// Layer-0 input: x [B][C][T] fp32 c-major -> bf16 t-major + fp32 t-major
__global__ __launch_bounds__(256) void transpose_cvt_in(
    const float* __restrict__ s, unsigned short* __restrict__ dh,
    float* __restrict__ df)
{
  __shared__ float tile[32][33];
  const int b = blockIdx.z;
  const int c0 = blockIdx.y * 32, t0 = blockIdx.x * 32;
  const int tx = threadIdx.x & 31, ty = threadIdx.x >> 5;
  const float* sp = s + ((size_t)b * C + c0) * T + t0;
#pragma unroll
  for (int i = 0; i < 4; ++i)
    tile[ty + i * 8][tx] = sp[(size_t)(ty + i * 8) * T + tx];
  __syncthreads();
  unsigned short* dph = dh + ((size_t)b * T + t0) * C + c0;
  float* dpf = df + ((size_t)b * T + t0) * C + c0;
#pragma unroll
  for (int i = 0; i < 4; ++i) {
    const float v = tile[tx][ty + i * 8];
    dph[(size_t)(ty + i * 8) * C + tx] = f2b(v);
    dpf[(size_t)(ty + i * 8) * C + tx] = v;
  }
}

// Final residual: fp32 t-major [B][T][C] -> fp32 c-major [B][C][T]
__global__ __launch_bounds__(256) void transpose_out(
    const float* __restrict__ s, float* __restrict__ d)
{
  __shared__ float tile[32][33];
  const int b = blockIdx.z;
  const int c0 = blockIdx.y * 32, t0 = blockIdx.x * 32;
  const int tx = threadIdx.x & 31, ty = threadIdx.x >> 5;
  const float* sp = s + ((size_t)b * T + t0) * C + c0;
#pragma unroll
  for (int i = 0; i < 4; ++i)
    tile[ty + i * 8][tx] = sp[(size_t)(ty + i * 8) * C + tx];
  __syncthreads();
  float* dp = d + ((size_t)b * C + c0) * T + t0;
#pragma unroll
  for (int i = 0; i < 4; ++i)
    dp[(size_t)(ty + i * 8) * T + tx] = tile[tx][ty + i * 8];
}

// ---------------------------------------------------------------------------
// QKVO weights fp32 [C][C] -> bf16 fragment-tiled. LDS-staged; nontemporal
// fp32 loads (single-use stream).
__global__ __launch_bounds__(256) void cvt_qkvo_tiled(
    const float* __restrict__ q, const float* __restrict__ k,
    const float* __restrict__ v, const float* __restrict__ o,
    unsigned short* __restrict__ dq, unsigned short* __restrict__ dk,
    unsigned short* __restrict__ dv, unsigned short* __restrict__ dov)
{
  __shared__ float lds[16][132];
  const int z = blockIdx.y;
  const size_t loff = (size_t)blockIdx.z * C * C;
  const float* s = (z == 0 ? q : z == 1 ? k : z == 2 ? v : o) + loff;
  unsigned short* d = (z == 0 ? dq : z == 1 ? dk : z == 2 ? dv : dov) + loff;
  constexpr int KST = C / 32;      // 24
  constexpr int KSG = KST / 4;     // 6
  const int mt = blockIdx.x / KSG;
  const int ksg = blockIdx.x % KSG;
  const int tid = threadIdx.x;
#pragma unroll
  for (int p = 0; p < 2; ++p) {
    const int f = tid + p * 256;
    const int row = f >> 5, c4 = f & 31;
    f32x4 vv = __builtin_nontemporal_load(
        (const f32x4*)(s + (size_t)(mt * 16 + row) * C + ksg * 128 + c4 * 4));
    *(f32x4*)&lds[row][c4 * 4] = vv;
  }
  __syncthreads();
  const int ksl = tid >> 6, lane = tid & 63;
  const int l15 = lane & 15, lhi = lane >> 4;
  float4 a = *(const float4*)&lds[l15][ksl * 32 + lhi * 8];
  float4 b = *(const float4*)&lds[l15][ksl * 32 + lhi * 8 + 4];
  sh8 u;
  u[0] = (short)f2b(a.x); u[1] = (short)f2b(a.y);
  u[2] = (short)f2b(a.z); u[3] = (short)f2b(a.w);
  u[4] = (short)f2b(b.x); u[5] = (short)f2b(b.y);
  u[6] = (short)f2b(b.z); u[7] = (short)f2b(b.w);
  *(sh8*)(d + ((size_t)(mt * KST + ksg * 4 + ksl) * 64 + lane) * 8) = u;
}

// FFN weights [O][Ci][3] fp32 -> 3 tap planes fragment-tiled. LDS-staged,
// nontemporal fp32 loads, vector ds_read, coalesced 16B writes.
__global__ __launch_bounds__(256) void cvt_ffn_tiled(
    const float* __restrict__ s1, const float* __restrict__ s2,
    unsigned short* __restrict__ d1, unsigned short* __restrict__ d2)
{
  __shared__ float lds[16][388];
  const int z = blockIdx.y;
  const int layer = blockIdx.z;
  const float* src = (z ? s2 : s1) + (size_t)layer * FF * C * 3;
  unsigned short* dst = (z ? d2 : d1) + (size_t)layer * 3 * FF * C;
  const int O  = z ? C : FF;
  const int Ci = z ? FF : C;
  const int KST = Ci >> 5;
  const int KSG = KST >> 2;
  const int mt = blockIdx.x / KSG;
  const int ksg = blockIdx.x % KSG;
  const int tid = threadIdx.x;
  const size_t rowlen = (size_t)Ci * 3;
#pragma unroll
  for (int p = 0; p < 6; ++p) {
    const int f = tid + p * 256;
    const int row = f / 96, c4 = f % 96;
    f32x4 vv = __builtin_nontemporal_load(
        (const f32x4*)(src + (size_t)(mt * 16 + row) * rowlen + ksg * 384 + c4 * 4));
    *(f32x4*)&lds[row][c4 * 4] = vv;
  }
  __syncthreads();
  const int ksl = tid >> 6, lane = tid & 63;
  const int l15 = lane & 15, lhi = lane >> 4;
  const int q0 = ksl * 96 + lhi * 24;
  float f[24];
#pragma unroll
  for (int kq = 0; kq < 6; ++kq) {
    float4 t4 = *(const float4*)&lds[l15][q0 + kq * 4];
    f[kq * 4 + 0] = t4.x; f[kq * 4 + 1] = t4.y;
    f[kq * 4 + 2] = t4.z; f[kq * 4 + 3] = t4.w;
  }
  const size_t fragoff = ((size_t)(mt * KST + ksg * 4 + ksl) * 64 + lane) * 8;
#pragma unroll
  for (int tap = 0; tap < 3; ++tap) {
    sh8 u;
#pragma unroll
    for (int j = 0; j < 8; ++j) u[j] = (short)f2b(f[j * 3 + tap]);
    *(sh8*)(dst + (size_t)tap * O * Ci + fragoff) = u;
  }
}

// ---------------------------------------------------------------------------
// 256-thread MFMA conv (BM=128 x BN∈{64,128}), 2-phase double-buffered.
// KBIN: input bf16 K-blocked [b][Cin/32][T][32] (contiguous loadB).
// KBOUT: bf16 output K-blocked (for hidh consumers).
template <int TAPS, int BN, int KSPLIT, bool GELU, bool MASK_OUT, bool OBF16,
          bool KBIN, bool KBOUT>
__global__ __launch_bounds__(256) void mfma_conv(
    const unsigned short* __restrict__ xin,
    const unsigned short* __restrict__ w0p, const unsigned short* __restrict__ w1p,
    const unsigned short* __restrict__ w2p,
    const float* __restrict__ b0, const float* __restrict__ b1,
    const float* __restrict__ b2,
    const float* __restrict__ mask,
    void* __restrict__ o0p, void* __restrict__ o1p, void* __restrict__ o2p,
    int Cin, int O, int tilesPerPlane, int nz)
{
  constexpr int ROWS_B = BN + TAPS - 1;
  constexpr int PB = 40;
  constexpr int NPASS = BN / 64;
  constexpr int NF = BN / 32;
  constexpr int NT = T / BN;
  __shared__ unsigned short Aw[2][TAPS * 8 * 512];
  __shared__ unsigned short Bx[2][ROWS_B * PB];

  const int nwg = gridDim.x;
  const int orig = blockIdx.x;
  const int wg = (orig & 7) * (nwg >> 3) + (orig >> 3);
  const int txt = wg % NT;
  const int rest = wg / NT;
  const int zz = rest % nz;
  const int ty = rest / nz;

  const int b  = zz / KSPLIT;
  const int kk = zz % KSPLIT;
  const int TOFF = (TAPS == 3) ? -1 : 0;
  const int t0 = txt * BN;
  const int plane = ty / tilesPerPlane;
  const int mt0 = (ty % tilesPerPlane) * 8;
  const int o0 = mt0 * 16;

  const int tid = threadIdx.x;
  const int lane = tid & 63, wid = tid >> 6;
  const int wm = wid >> 1, wn = wid & 1;
  const int l15 = lane & 15, lhi = lane >> 4;
  const int bmask = b * T;

  const unsigned short* wsel = plane == 0 ? w0p : (plane == 1 ? w1p : w2p);
  const float* bp = plane == 0 ? b0 : (plane == 1 ? b1 : b2);

  const int KST = Cin >> 5;
  const int kchunk = KST / KSPLIT;
  const int ks0 = kk * kchunk, ks1 = ks0 + kchunk;
  const int OT = O >> 4;

  const unsigned short* xb_ = xin + (size_t)b * T * Cin;
  const unsigned short* xkb = xin + (size_t)b * KST * T * 32;

  sh8 breg[NPASS], breg2;
  auto stageA = [&](int ks, int buf) {
#pragma unroll
    for (int tap = 0; tap < TAPS; ++tap) {
#pragma unroll
      for (int j = 0; j < 2; ++j) {
        const int rt = wid * 2 + j;
        const unsigned short* src =
            wsel + (((size_t)tap * OT + mt0 + rt) * KST + ks) * 512 + lane * 8;
        gload_lds16(src, &Aw[buf][(tap * 8 + rt) * 512]);
      }
    }
  };
  auto loadB = [&](int ks) {
    const int c0 = ks << 5;
    const unsigned short* kbase = xkb + (size_t)ks * T * 32;
#pragma unroll
    for (int p = 0; p < NPASS; ++p) {
      const int idx = tid + p * 256;
      const int row = idx >> 2, c8 = (idx & 3) << 3;
      const int tsrc = t0 + row + TOFF;
      breg[p] = (sh8)0;
      if ((unsigned)tsrc < (unsigned)T) {
        if constexpr (KBIN)
          breg[p] = *(const sh8*)(kbase + (size_t)tsrc * 32 + c8);
        else
          breg[p] = *(const sh8*)(xb_ + (size_t)tsrc * Cin + c0 + c8);
      }
    }
    if constexpr (TAPS == 3) {
      breg2 = (sh8)0;
      if (tid < 8) {
        const int row = BN + (tid >> 2), c8 = (tid & 3) << 3;
        const int ts2 = t0 + row + TOFF;
        if ((unsigned)ts2 < (unsigned)T) {
          if constexpr (KBIN)
            breg2 = *(const sh8*)(kbase + (size_t)ts2 * 32 + c8);
          else
            breg2 = *(const sh8*)(xb_ + (size_t)ts2 * Cin + c0 + c8);
        }
      }
    }
  };
  auto writeB = [&](int buf) {
#pragma unroll
    for (int p = 0; p < NPASS; ++p) {
      const int idx = tid + p * 256;
      *(sh8*)&Bx[buf][(idx >> 2) * PB + ((idx & 3) << 3)] = breg[p];
    }
    if constexpr (TAPS == 3) {
      if (tid < 8)
        *(sh8*)&Bx[buf][(BN + (tid >> 2)) * PB + ((tid & 3) << 3)] = breg2;
    }
  };

  f32x4 acc[4][NF] = {};

  int cur = 0;
  stageA(ks0, 0);
  loadB(ks0);
  writeB(0);
  __syncthreads();

  for (int ks = ks0; ks < ks1; ++ks) {
    const int nxt = cur ^ 1;
    const bool more = (ks + 1 < ks1);
    if (more) { stageA(ks + 1, nxt); loadB(ks + 1); }
#pragma unroll
    for (int tap = 0; tap < TAPS; ++tap) {
      sh8 af[4], bfr[NF];
#pragma unroll
      for (int m = 0; m < 4; ++m)
        af[m] = *(const sh8*)&Aw[cur][(tap * 8 + wm * 4 + m) * 512 + lane * 8];
#pragma unroll
      for (int n = 0; n < NF; ++n)
        bfr[n] = *(const sh8*)&Bx[cur][(wn * (NF * 16) + n * 16 + l15 + tap) * PB + lhi * 8];
#pragma unroll
      for (int m = 0; m < 4; ++m)
#pragma unroll
        for (int n = 0; n < NF; ++n)
          acc[m][n] = __builtin_amdgcn_mfma_f32_16x16x32_bf16(
              af[m], bfr[n], acc[m][n], 0, 0, 0);
    }
    if (more) writeB(nxt);
    __syncthreads();
    cur = nxt;
  }

  void* obase = plane == 0 ? o0p : (plane == 1 ? o1p : o2p);
  unsigned short* oph = (unsigned short*)obase + (size_t)b * T * O;
  unsigned short* opk = (unsigned short*)obase + (size_t)b * (O >> 5) * T * 32;
  float* opf = (float*)obase + ((size_t)kk * B + b) * (size_t)T * O;
#pragma unroll
  for (int m = 0; m < 4; ++m) {
    const int o = o0 + (wm * 4 + m) * 16 + (lhi << 2);
#pragma unroll
    for (int n = 0; n < NF; ++n) {
      const int t = t0 + wn * (NF * 16) + n * 16 + l15;
      const float mk = MASK_OUT ? mask[bmask + t] : 1.f;
      float v[4];
#pragma unroll
      for (int r4 = 0; r4 < 4; ++r4) {
        float x = acc[m][n][r4];
        if (KSPLIT > 1) {
          if (kk == 0) x += bp[o + r4];
        } else {
          x += bp[o + r4];
        }
        if (GELU) x = gelu_exact(x);
        if (MASK_OUT) x *= mk;
        v[r4] = x;
      }
      if constexpr (OBF16) {
        ushort4 hz;
        hz.x = f2b(v[0]); hz.y = f2b(v[1]); hz.z = f2b(v[2]); hz.w = f2b(v[3]);
        if constexpr (KBOUT)
          *(ushort4*)(opk + ((size_t)(o >> 5) * T + t) * 32 + (o & 31)) = hz;
        else
          *(ushort4*)(oph + (size_t)t * O + o) = hz;
      } else {
        *(float4*)(opf + (size_t)t * O + o) = make_float4(v[0], v[1], v[2], v[3]);
      }
    }
  }
}

// ---------------------------------------------------------------------------
// Fused attention with 2-phase K/V prefetch. q/k/v t-major bf16 [B][T][C];
// output K-blocked bf16 [B][C/32][T][32].
__global__ __launch_bounds__(256) void fused_attn(
    const unsigned short* __restrict__ qg,
    const unsigned short* __restrict__ kg,
    const unsigned short* __restrict__ vg,
    const float* __restrict__ mask,
    const float* __restrict__ ek,
    const float* __restrict__ ev,
    unsigned short* __restrict__ outp)
{
  constexpr int PITCH = 72;
  __shared__ unsigned short Qs[64 * PITCH];
  __shared__ unsigned short Ks[2][64 * PITCH];
  __shared__ unsigned short Vs[2][64 * PITCH];
  __shared__ unsigned short Ps[64 * PITCH];
  __shared__ float eks[D * 9], evs[D * 9];
  __shared__ float qekl[64 * 12];
  __shared__ float mks[2][64];

  const int t0 = blockIdx.x * 64;
  const int bh = blockIdx.y;
  const int b = bh / H, h = bh % H;
  const int tid = threadIdx.x;
  const int lane = tid & 63, w = tid >> 6;
  const int l15 = lane & 15, lhi = lane >> 4;

  const size_t base = (size_t)b * T * C + h * D;
  const unsigned short* qh = qg + base;
  const unsigned short* kh = kg + base;
  const unsigned short* vh = vg + base;

  for (int e = tid; e < D * 9; e += 256) { eks[e] = ek[e]; evs[e] = ev[e]; }
  {
    const int tl = tid & 63, d0 = (tid >> 6) << 4;
    const unsigned short* src = qh + (size_t)(t0 + tl) * C + d0;
    *(sh8*)&Qs[tl * PITCH + d0]     = *(const sh8*)(src);
    *(sh8*)&Qs[tl * PITCH + d0 + 8] = *(const sh8*)(src + 8);
  }
  __syncthreads();
  {
    const int tl = tid & 63, g = tid >> 6;
    for (int j = g; j < 9; j += 4) {
      float a = 0.f;
      for (int d = 0; d < D; ++d)
        a = fmaf(b2f(Qs[tl * PITCH + d]), eks[d * 9 + j], a);
      qekl[tl * 12 + j] = a * 0.125f;
    }
  }
  const int t_loc = w * 16 + l15;
  const int t = t0 + t_loc;
  const float mask_t = mask[b * T + t];
  const sh8 bq0 = *(const sh8*)&Qs[t_loc * PITCH + lhi * 8];
  const sh8 bq1 = *(const sh8*)&Qs[t_loc * PITCH + 32 + lhi * 8];

  const int sl = tid & 63, d0s = (tid >> 6) << 4;
  {
    const unsigned short* srck = kh + (size_t)sl * C + d0s;
    *(sh8*)&Ks[0][sl * PITCH + d0s]     = *(const sh8*)(srck);
    *(sh8*)&Ks[0][sl * PITCH + d0s + 8] = *(const sh8*)(srck + 8);
    const unsigned short* srcv = vh + (size_t)sl * C + d0s;
    sh8 u0 = *(const sh8*)(srcv);
    sh8 u1 = *(const sh8*)(srcv + 8);
#pragma unroll
    for (int j = 0; j < 8; ++j) Vs[0][(d0s + j) * PITCH + sl] = (unsigned short)u0[j];
#pragma unroll
    for (int j = 0; j < 8; ++j) Vs[0][(d0s + 8 + j) * PITCH + sl] = (unsigned short)u1[j];
    if (tid < 64) mks[0][tid] = mask[b * T + tid];
  }
  __syncthreads();

  float m_run = -1e30f, l_run = 0.f;
  f32x4 oacc[4] = {};
  int cur = 0;
  sh8 kr0, kr1, vr0, vr1;
  float mkr = 0.f;

  for (int s0 = 0; s0 < T; s0 += 64) {
    const int nxt = cur ^ 1;
    const bool more = (s0 + 64 < T);
    if (more) {
      const unsigned short* srck = kh + (size_t)(s0 + 64 + sl) * C + d0s;
      kr0 = *(const sh8*)(srck);
      kr1 = *(const sh8*)(srck + 8);
      const unsigned short* srcv = vh + (size_t)(s0 + 64 + sl) * C + d0s;
      vr0 = *(const sh8*)(srcv);
      vr1 = *(const sh8*)(srcv + 8);
      if (tid < 64) mkr = mask[b * T + s0 + 64 + tid];
    }

    float p[16];
#pragma unroll
    for (int n = 0; n < 4; ++n) {
      const sh8 a0 = *(const sh8*)&Ks[cur][(n * 16 + l15) * PITCH + lhi * 8];
      const sh8 a1 = *(const sh8*)&Ks[cur][(n * 16 + l15) * PITCH + 32 + lhi * 8];
      f32x4 acc = {};
      __builtin_amdgcn_s_setprio(1);
      acc = __builtin_amdgcn_mfma_f32_16x16x32_bf16(a0, bq0, acc, 0, 0, 0);
      acc = __builtin_amdgcn_mfma_f32_16x16x32_bf16(a1, bq1, acc, 0, 0, 0);
      __builtin_amdgcn_s_setprio(0);
#pragma unroll
      for (int r = 0; r < 4; ++r) {
        const int s = s0 + n * 16 + lhi * 4 + r;
        float v = acc[r] * 0.125f;
        const int j = s - t + 4;
        if ((unsigned)j < 9u) v += qekl[t_loc * 12 + j];
        if (mask_t * mks[cur][s - s0] == 0.f) v = -10000.0f;
        p[n * 4 + r] = v;
      }
    }
    float mloc = p[0];
#pragma unroll
    for (int i = 1; i < 16; ++i) mloc = fmaxf(mloc, p[i]);
    mloc = fmaxf(mloc, __shfl_xor(mloc, 16));
    mloc = fmaxf(mloc, __shfl_xor(mloc, 32));
    const float m_new = fmaxf(m_run, mloc);
    const float f = __expf(m_run - m_new);
    float sloc = 0.f;
#pragma unroll
    for (int i = 0; i < 16; ++i) { p[i] = __expf(p[i] - m_new); sloc += p[i]; }
    sloc += __shfl_xor(sloc, 16);
    sloc += __shfl_xor(sloc, 32);
    l_run = l_run * f + sloc;
    m_run = m_new;
#pragma unroll
    for (int m = 0; m < 4; ++m)
#pragma unroll
      for (int r = 0; r < 4; ++r) oacc[m][r] *= f;
#pragma unroll
    for (int n = 0; n < 4; ++n) {
      uint2 pk;
      pk.x = (unsigned)f2b(p[n * 4 + 0]) | ((unsigned)f2b(p[n * 4 + 1]) << 16);
      pk.y = (unsigned)f2b(p[n * 4 + 2]) | ((unsigned)f2b(p[n * 4 + 3]) << 16);
      *(uint2*)&Ps[t_loc * PITCH + n * 16 + lhi * 4] = pk;
    }
    asm volatile("s_waitcnt lgkmcnt(0)" ::: "memory");
    const sh8 bp0 = *(const sh8*)&Ps[t_loc * PITCH + lhi * 8];
    const sh8 bp1 = *(const sh8*)&Ps[t_loc * PITCH + 32 + lhi * 8];
    __builtin_amdgcn_s_setprio(1);
#pragma unroll
    for (int m = 0; m < 4; ++m) {
      const sh8 a0 = *(const sh8*)&Vs[cur][(m * 16 + l15) * PITCH + lhi * 8];
      const sh8 a1 = *(const sh8*)&Vs[cur][(m * 16 + l15) * PITCH + 32 + lhi * 8];
      oacc[m] = __builtin_amdgcn_mfma_f32_16x16x32_bf16(a0, bp0, oacc[m], 0, 0, 0);
      oacc[m] = __builtin_amdgcn_mfma_f32_16x16x32_bf16(a1, bp1, oacc[m], 0, 0, 0);
    }
    __builtin_amdgcn_s_setprio(0);
    if (t + 4 >= s0 && t < s0 + 68) {
#pragma unroll
      for (int j = 0; j < 9; ++j) {
        const int s = t + j - 4;
        if (s >= s0 && s < s0 + 64) {
          const float pv = b2f(Ps[t_loc * PITCH + (s - s0)]);
#pragma unroll
          for (int m = 0; m < 4; ++m)
#pragma unroll
            for (int r = 0; r < 4; ++r)
              oacc[m][r] = fmaf(pv, evs[(m * 16 + lhi * 4 + r) * 9 + j], oacc[m][r]);
        }
      }
    }
    if (more) {
      *(sh8*)&Ks[nxt][sl * PITCH + d0s]     = kr0;
      *(sh8*)&Ks[nxt][sl * PITCH + d0s + 8] = kr1;
#pragma unroll
      for (int j = 0; j < 8; ++j) Vs[nxt][(d0s + j) * PITCH + sl] = (unsigned short)vr0[j];
#pragma unroll
      for (int j = 0; j < 8; ++j) Vs[nxt][(d0s + 8 + j) * PITCH + sl] = (unsigned short)vr1[j];
      if (tid < 64) mks[nxt][tid] = mkr;
    }
    __syncthreads();
    cur = nxt;
  }
  const float invl = 1.f / l_run;
  unsigned short* okb = outp + (size_t)b * (C >> 5) * T * 32;
#pragma unroll
  for (int m = 0; m < 4; ++m) {
    ushort4 hz;
    hz.x = f2b(oacc[m][0] * invl);
    hz.y = f2b(oacc[m][1] * invl);
    hz.z = f2b(oacc[m][2] * invl);
    hz.w = f2b(oacc[m][3] * invl);
    const int c = h * D + m * 16 + lhi * 4;
    *(ushort4*)(okb + ((size_t)(c >> 5) * T + t) * 32 + (c & 31)) = hz;
  }
}

// ---------------------------------------------------------------------------
// Wave-per-t add+layernorm, everything t-major.
template <int NP, bool MASKY, bool MASKF>
__global__ __launch_bounds__(256) void add_norm_wave(
    const float* __restrict__ xr, const float* __restrict__ ypart,
    const float* __restrict__ g, const float* __restrict__ bta,
    const float* __restrict__ mask, float* __restrict__ dst,
    unsigned short* __restrict__ dsth)
{
  const int b = blockIdx.y;
  const int t = blockIdx.x * 4 + (threadIdx.x >> 6);
  const int lane = threadIdx.x & 63;
  const float mkt = mask[b * T + t];
  const size_t rowoff = ((size_t)b * T + t) * C;
  const int ci0 = lane * 12;

  float vv[12];
  float sum = 0.f, sq = 0.f;
#pragma unroll
  for (int q = 0; q < 3; ++q) {
    const int ci = ci0 + q * 4;
    float4 xv = *(const float4*)(xr + rowoff + ci);
    float4 yv = make_float4(0.f, 0.f, 0.f, 0.f);
#pragma unroll
    for (int p = 0; p < NP; ++p) {
      float4 t4 = *(const float4*)(ypart + (size_t)p * B * T * C + rowoff + ci);
      yv.x += t4.x; yv.y += t4.y; yv.z += t4.z; yv.w += t4.w;
    }
    if (MASKY) { yv.x *= mkt; yv.y *= mkt; yv.z *= mkt; yv.w *= mkt; }
    const float v0 = xv.x + yv.x, v1 = xv.y + yv.y;
    const float v2 = xv.z + yv.z, v3 = xv.w + yv.w;
    vv[q * 4 + 0] = v0; vv[q * 4 + 1] = v1; vv[q * 4 + 2] = v2; vv[q * 4 + 3] = v3;
    sum += v0 + v1 + v2 + v3;
    sq = fmaf(v0, v0, fmaf(v1, v1, fmaf(v2, v2, fmaf(v3, v3, sq))));
  }
#pragma unroll
  for (int o = 32; o > 0; o >>= 1) {
    sum += __shfl_xor(sum, o);
    sq += __shfl_xor(sq, o);
  }
  const float m = sum * (1.f / C);
  const float rs = rsqrtf(sq * (1.f / C) - m * m + 1e-5f);
#pragma unroll
  for (int q = 0; q < 3; ++q) {
    const int ci = ci0 + q * 4;
    float4 gv = *(const float4*)(g + ci);
    float4 bv = *(const float4*)(bta + ci);
    float o0 = (vv[q * 4 + 0] - m) * rs * gv.x + bv.x;
    float o1 = (vv[q * 4 + 1] - m) * rs * gv.y + bv.y;
    float o2 = (vv[q * 4 + 2] - m) * rs * gv.z + bv.z;
    float o3 = (vv[q * 4 + 3] - m) * rs * gv.w + bv.w;
    if (MASKF) { o0 *= mkt; o1 *= mkt; o2 *= mkt; o3 *= mkt; }
    *(float4*)(dst + rowoff + ci) = make_float4(o0, o1, o2, o3);
    const float hm = MASKF ? 1.f : mkt;
    ushort4 hz;
    hz.x = f2b(o0 * hm); hz.y = f2b(o1 * hm); hz.z = f2b(o2 * hm); hz.w = f2b(o3 * hm);
    *(ushort4*)(dsth + rowoff + ci) = hz;
  }
}

}  // namespace

extern "C" void kernel_launch(void* const* d_in, const int* in_sizes, int n_in,
                              void* d_out, int out_size, void* d_ws, size_t ws_size,
                              hipStream_t stream) {
  const float* x_in = (const float*)d_in[0];
  const float* mask = (const float*)d_in[1];
  const float* Wq = (const float*)d_in[2];
  const float* bq = (const float*)d_in[3];
  const float* Wk = (const float*)d_in[4];
  const float* bk = (const float*)d_in[5];
  const float* Wv = (const float*)d_in[6];
  const float* bv = (const float*)d_in[7];
  const float* Wo = (const float*)d_in[8];
  const float* bo = (const float*)d_in[9];
  const float* ek = (const float*)d_in[10];
  const float* ev = (const float*)d_in[11];
  const float* w1 = (const float*)d_in[12];
  const float* b1 = (const float*)d_in[13];
  const float* w2 = (const float*)d_in[14];
  const float* b2 = (const float*)d_in[15];
  const float* n1g = (const float*)d_in[16];
  const float* n1b = (const float*)d_in[17];
  const float* n2g = (const float*)d_in[18];
  const float* n2b = (const float*)d_in[19];

  float* ws = (float*)d_ws;
  const size_t SZ_X = (size_t)B * C * T;
  const size_t SZ_W1 = (size_t)3 * FF * C;
  float* xr    = ws;
  float* xr1   = xr + SZ_X;
  float* ypart = xr1 + SZ_X;
  unsigned short* xbh = (unsigned short*)(ypart + 4 * SZ_X);
  unsigned short* xfh = xbh + SZ_X;
  unsigned short* qbh = xfh + SZ_X;
  unsigned short* kbh = qbh + SZ_X;
  unsigned short* vbh = kbh + SZ_X;
  unsigned short* hidh = vbh + SZ_X;
  unsigned short* w1t = hidh + (size_t)B * FF * T;
  unsigned short* w2t = w1t + (size_t)NL * SZ_W1;
  unsigned short* wqt = w2t + (size_t)NL * SZ_W1;
  unsigned short* wkt = wqt + (size_t)NL * C * C;
  unsigned short* wvt = wkt + (size_t)NL * C * C;
  unsigned short* wot = wvt + (size_t)NL * C * C;
  float* outp = (float*)d_out;

  const dim3 blk(256);
  transpose_cvt_in<<<dim3(T / 32, C / 32, B), blk, 0, stream>>>(x_in, xbh, xr);
  cvt_qkvo_tiled<<<dim3((C / 16) * (C / 128), 4, NL), blk, 0, stream>>>(
      Wq, Wk, Wv, Wo, wqt, wkt, wvt, wot);
  cvt_ffn_tiled<<<dim3((FF / 16) * (C / 128), 2, NL), blk, 0, stream>>>(
      w1, w2, w1t, w2t);

  for (int i = 0; i < NL; ++i) {
    const size_t wOff = (size_t)i * C * C;
    const unsigned short* w1l = w1t + (size_t)i * SZ_W1;
    const unsigned short* w2l = w2t + (size_t)i * SZ_W1;
    // QKV projection -> bf16 q,k,v t-major   (576 blocks, BN=64)
    mfma_conv<1, 64, 1, false, false, true, false, false>
        <<<dim3(8 * 18 * 4), blk, 0, stream>>>(
        xbh, wqt + wOff, wkt + wOff, wvt + wOff,
        bq + i * C, bk + i * C, bv + i * C, mask,
        qbh, kbh, vbh, C, C, 6, 4);
    // fused attention -> K-blocked bf16
    fused_attn<<<dim3(T / 64, B * H), blk, 0, stream>>>(
        qbh, kbh, vbh, mask, ek + (size_t)i * D * 9, ev + (size_t)i * D * 9, hidh);
    // Wo projection: K-blocked input, split-K3 -> fp32 partials (576 blocks)
    mfma_conv<1, 64, 3, false, false, false, true, false>
        <<<dim3(8 * 6 * 12), blk, 0, stream>>>(
        hidh, wot + wOff, wot + wOff, wot + wOff,
        bo + i * C, bo + i * C, bo + i * C, mask,
        ypart, ypart, ypart, C, C, 6, 12);
    add_norm_wave<3, false, false><<<dim3(T / 4, B), blk, 0, stream>>>(
        xr, ypart, n1g + i * C, n1b + i * C, mask, xr1, xfh);
    // FFN up: t-major in, GELU+mask, K-blocked bf16 out   (384 blocks)
    mfma_conv<3, 128, 1, true, true, true, false, true>
        <<<dim3(4 * 24 * 4), blk, 0, stream>>>(
        xfh, w1l, w1l, w1l, b1 + i * FF, b1 + i * FF, b1 + i * FF, mask,
        hidh, hidh, hidh, C, FF, 24, 4);
    // FFN down: K-blocked in, split-K4 -> fp32 partials   (384 blocks)
    mfma_conv<3, 128, 4, false, false, false, true, false>
        <<<dim3(4 * 6 * 16), blk, 0, stream>>>(
        hidh, w2l, w2l, w2l, b2 + i * C, b2 + i * C, b2 + i * C, mask,
        ypart, ypart, ypart, FF, C, 6, 16);
    add_norm_wave<4, true, true><<<dim3(T / 4, B), blk, 0, stream>>>(
        xr1, ypart, n2g + i * C, n2b + i * C, mask, xr, xbh);
  }
  transpose_out<<<dim3(T / 32, C / 32, B), blk, 0, stream>>>(xr, outp);
}

// Round 19
// 1065.778 us; speedup vs baseline: 1.6356x; 1.0365x over previous
//
#include <hip/hip_runtime.h>
#include <cstddef>

namespace {

constexpr int B  = 4;
constexpr int C  = 768;
constexpr int T  = 512;
constexpr int H  = 12;
constexpr int D  = 64;
constexpr int NL = 6;
constexpr int W  = 4;
constexpr int FF = 3072;

typedef __attribute__((ext_vector_type(8))) short sh8;
typedef __attribute__((ext_vector_type(4))) float f32x4;

__device__ inline float gelu_exact(float x) {
  return 0.5f * x * (1.0f + erff(x * 0.70710678118654752440f));
}
__device__ inline unsigned short f2b(float f) {
  unsigned u = __float_as_uint(f);
  unsigned r = (u + 0x7fffu + ((u >> 16) & 1u)) >> 16;
  return (unsigned short)r;
}
__device__ inline float b2f(unsigned short u) {
  return __uint_as_float((unsigned)u << 16);
}
__device__ inline void gload_lds16(const void* g, void* l) {
  __builtin_amdgcn_global_load_lds(
      (const __attribute__((address_space(1))) unsigned int*)g,
      (__attribute__((address_space(3))) unsigned int*)l, 16, 0, 0);
}

// ---------------------------------------------------------------------------
// Layer-0 input: x [B][C][T] fp32 c-major -> bf16 t-major + fp32 t-major
__global__ __launch_bounds__(256) void transpose_cvt_in(
    const float* __restrict__ s, unsigned short* __restrict__ dh,
    float* __restrict__ df)
{
  __shared__ float tile[32][33];
  const int b = blockIdx.z;
  const int c0 = blockIdx.y * 32, t0 = blockIdx.x * 32;
  const int tx = threadIdx.x & 31, ty = threadIdx.x >> 5;
  const float* sp = s + ((size_t)b * C + c0) * T + t0;
#pragma unroll
  for (int i = 0; i < 4; ++i)
    tile[ty + i * 8][tx] = sp[(size_t)(ty + i * 8) * T + tx];
  __syncthreads();
  unsigned short* dph = dh + ((size_t)b * T + t0) * C + c0;
  float* dpf = df + ((size_t)b * T + t0) * C + c0;
#pragma unroll
  for (int i = 0; i < 4; ++i) {
    const float v = tile[tx][ty + i * 8];
    dph[(size_t)(ty + i * 8) * C + tx] = f2b(v);
    dpf[(size_t)(ty + i * 8) * C + tx] = v;
  }
}

// Final residual: fp32 t-major [B][T][C] -> fp32 c-major [B][C][T]
__global__ __launch_bounds__(256) void transpose_out(
    const float* __restrict__ s, float* __restrict__ d)
{
  __shared__ float tile[32][33];
  const int b = blockIdx.z;
  const int c0 = blockIdx.y * 32, t0 = blockIdx.x * 32;
  const int tx = threadIdx.x & 31, ty = threadIdx.x >> 5;
  const float* sp = s + ((size_t)b * T + t0) * C + c0;
#pragma unroll
  for (int i = 0; i < 4; ++i)
    tile[ty + i * 8][tx] = sp[(size_t)(ty + i * 8) * C + tx];
  __syncthreads();
  float* dp = d + ((size_t)b * C + c0) * T + t0;
#pragma unroll
  for (int i = 0; i < 4; ++i)
    dp[(size_t)(ty + i * 8) * T + tx] = tile[tx][ty + i * 8];
}

// ---------------------------------------------------------------------------
// QKVO weights fp32 [C][C] -> bf16 fragment-tiled. LDS-staged; nontemporal.
__global__ __launch_bounds__(256) void cvt_qkvo_tiled(
    const float* __restrict__ q, const float* __restrict__ k,
    const float* __restrict__ v, const float* __restrict__ o,
    unsigned short* __restrict__ dq, unsigned short* __restrict__ dk,
    unsigned short* __restrict__ dv, unsigned short* __restrict__ dov)
{
  __shared__ float lds[16][132];
  const int z = blockIdx.y;
  const size_t loff = (size_t)blockIdx.z * C * C;
  const float* s = (z == 0 ? q : z == 1 ? k : z == 2 ? v : o) + loff;
  unsigned short* d = (z == 0 ? dq : z == 1 ? dk : z == 2 ? dv : dov) + loff;
  constexpr int KST = C / 32;
  constexpr int KSG = KST / 4;
  const int mt = blockIdx.x / KSG;
  const int ksg = blockIdx.x % KSG;
  const int tid = threadIdx.x;
#pragma unroll
  for (int p = 0; p < 2; ++p) {
    const int f = tid + p * 256;
    const int row = f >> 5, c4 = f & 31;
    f32x4 vv = __builtin_nontemporal_load(
        (const f32x4*)(s + (size_t)(mt * 16 + row) * C + ksg * 128 + c4 * 4));
    *(f32x4*)&lds[row][c4 * 4] = vv;
  }
  __syncthreads();
  const int ksl = tid >> 6, lane = tid & 63;
  const int l15 = lane & 15, lhi = lane >> 4;
  float4 a = *(const float4*)&lds[l15][ksl * 32 + lhi * 8];
  float4 b = *(const float4*)&lds[l15][ksl * 32 + lhi * 8 + 4];
  sh8 u;
  u[0] = (short)f2b(a.x); u[1] = (short)f2b(a.y);
  u[2] = (short)f2b(a.z); u[3] = (short)f2b(a.w);
  u[4] = (short)f2b(b.x); u[5] = (short)f2b(b.y);
  u[6] = (short)f2b(b.z); u[7] = (short)f2b(b.w);
  *(sh8*)(d + ((size_t)(mt * KST + ksg * 4 + ksl) * 64 + lane) * 8) = u;
}

// FFN weights [O][Ci][3] fp32 -> 3 tap planes fragment-tiled.
__global__ __launch_bounds__(256) void cvt_ffn_tiled(
    const float* __restrict__ s1, const float* __restrict__ s2,
    unsigned short* __restrict__ d1, unsigned short* __restrict__ d2)
{
  __shared__ float lds[16][388];
  const int z = blockIdx.y;
  const int layer = blockIdx.z;
  const float* src = (z ? s2 : s1) + (size_t)layer * FF * C * 3;
  unsigned short* dst = (z ? d2 : d1) + (size_t)layer * 3 * FF * C;
  const int O  = z ? C : FF;
  const int Ci = z ? FF : C;
  const int KST = Ci >> 5;
  const int KSG = KST >> 2;
  const int mt = blockIdx.x / KSG;
  const int ksg = blockIdx.x % KSG;
  const int tid = threadIdx.x;
  const size_t rowlen = (size_t)Ci * 3;
#pragma unroll
  for (int p = 0; p < 6; ++p) {
    const int f = tid + p * 256;
    const int row = f / 96, c4 = f % 96;
    f32x4 vv = __builtin_nontemporal_load(
        (const f32x4*)(src + (size_t)(mt * 16 + row) * rowlen + ksg * 384 + c4 * 4));
    *(f32x4*)&lds[row][c4 * 4] = vv;
  }
  __syncthreads();
  const int ksl = tid >> 6, lane = tid & 63;
  const int l15 = lane & 15, lhi = lane >> 4;
  const int q0 = ksl * 96 + lhi * 24;
  float f[24];
#pragma unroll
  for (int kq = 0; kq < 6; ++kq) {
    float4 t4 = *(const float4*)&lds[l15][q0 + kq * 4];
    f[kq * 4 + 0] = t4.x; f[kq * 4 + 1] = t4.y;
    f[kq * 4 + 2] = t4.z; f[kq * 4 + 3] = t4.w;
  }
  const size_t fragoff = ((size_t)(mt * KST + ksg * 4 + ksl) * 64 + lane) * 8;
#pragma unroll
  for (int tap = 0; tap < 3; ++tap) {
    sh8 u;
#pragma unroll
    for (int j = 0; j < 8; ++j) u[j] = (short)f2b(f[j * 3 + tap]);
    *(sh8*)(dst + (size_t)tap * O * Ci + fragoff) = u;
  }
}

// ---------------------------------------------------------------------------
// 256-thread MFMA conv (BM=128 x BN∈{64,128}), 2-phase double-buffered.
// KBIN: input bf16 K-blocked [b][Cin/32][T][32]. KBOUT: K-blocked bf16 out.
// KSPLIT>1 (non-OBF16): writes BF16 partials [KSPLIT][B][T][O] (halved
// traffic; summed in fp32 by add_norm).
template <int TAPS, int BN, int KSPLIT, bool GELU, bool MASK_OUT, bool OBF16,
          bool KBIN, bool KBOUT>
__global__ __launch_bounds__(256) void mfma_conv(
    const unsigned short* __restrict__ xin,
    const unsigned short* __restrict__ w0p, const unsigned short* __restrict__ w1p,
    const unsigned short* __restrict__ w2p,
    const float* __restrict__ b0, const float* __restrict__ b1,
    const float* __restrict__ b2,
    const float* __restrict__ mask,
    void* __restrict__ o0p, void* __restrict__ o1p, void* __restrict__ o2p,
    int Cin, int O, int tilesPerPlane, int nz)
{
  constexpr int ROWS_B = BN + TAPS - 1;
  constexpr int PB = 40;
  constexpr int NPASS = BN / 64;
  constexpr int NF = BN / 32;
  constexpr int NT = T / BN;
  __shared__ unsigned short Aw[2][TAPS * 8 * 512];
  __shared__ unsigned short Bx[2][ROWS_B * PB];

  const int nwg = gridDim.x;
  const int orig = blockIdx.x;
  const int wg = (orig & 7) * (nwg >> 3) + (orig >> 3);
  const int txt = wg % NT;
  const int rest = wg / NT;
  const int zz = rest % nz;
  const int ty = rest / nz;

  const int b  = zz / KSPLIT;
  const int kk = zz % KSPLIT;
  const int TOFF = (TAPS == 3) ? -1 : 0;
  const int t0 = txt * BN;
  const int plane = ty / tilesPerPlane;
  const int mt0 = (ty % tilesPerPlane) * 8;
  const int o0 = mt0 * 16;

  const int tid = threadIdx.x;
  const int lane = tid & 63, wid = tid >> 6;
  const int wm = wid >> 1, wn = wid & 1;
  const int l15 = lane & 15, lhi = lane >> 4;
  const int bmask = b * T;

  const unsigned short* wsel = plane == 0 ? w0p : (plane == 1 ? w1p : w2p);
  const float* bp = plane == 0 ? b0 : (plane == 1 ? b1 : b2);

  const int KST = Cin >> 5;
  const int kchunk = KST / KSPLIT;
  const int ks0 = kk * kchunk, ks1 = ks0 + kchunk;
  const int OT = O >> 4;

  const unsigned short* xb_ = xin + (size_t)b * T * Cin;
  const unsigned short* xkb = xin + (size_t)b * KST * T * 32;

  sh8 breg[NPASS], breg2;
  auto stageA = [&](int ks, int buf) {
#pragma unroll
    for (int tap = 0; tap < TAPS; ++tap) {
#pragma unroll
      for (int j = 0; j < 2; ++j) {
        const int rt = wid * 2 + j;
        const unsigned short* src =
            wsel + (((size_t)tap * OT + mt0 + rt) * KST + ks) * 512 + lane * 8;
        gload_lds16(src, &Aw[buf][(tap * 8 + rt) * 512]);
      }
    }
  };
  auto loadB = [&](int ks) {
    const int c0 = ks << 5;
    const unsigned short* kbase = xkb + (size_t)ks * T * 32;
#pragma unroll
    for (int p = 0; p < NPASS; ++p) {
      const int idx = tid + p * 256;
      const int row = idx >> 2, c8 = (idx & 3) << 3;
      const int tsrc = t0 + row + TOFF;
      breg[p] = (sh8)0;
      if ((unsigned)tsrc < (unsigned)T) {
        if constexpr (KBIN)
          breg[p] = *(const sh8*)(kbase + (size_t)tsrc * 32 + c8);
        else
          breg[p] = *(const sh8*)(xb_ + (size_t)tsrc * Cin + c0 + c8);
      }
    }
    if constexpr (TAPS == 3) {
      breg2 = (sh8)0;
      if (tid < 8) {
        const int row = BN + (tid >> 2), c8 = (tid & 3) << 3;
        const int ts2 = t0 + row + TOFF;
        if ((unsigned)ts2 < (unsigned)T) {
          if constexpr (KBIN)
            breg2 = *(const sh8*)(kbase + (size_t)ts2 * 32 + c8);
          else
            breg2 = *(const sh8*)(xb_ + (size_t)ts2 * Cin + c0 + c8);
        }
      }
    }
  };
  auto writeB = [&](int buf) {
#pragma unroll
    for (int p = 0; p < NPASS; ++p) {
      const int idx = tid + p * 256;
      *(sh8*)&Bx[buf][(idx >> 2) * PB + ((idx & 3) << 3)] = breg[p];
    }
    if constexpr (TAPS == 3) {
      if (tid < 8)
        *(sh8*)&Bx[buf][(BN + (tid >> 2)) * PB + ((tid & 3) << 3)] = breg2;
    }
  };

  f32x4 acc[4][NF] = {};

  int cur = 0;
  stageA(ks0, 0);
  loadB(ks0);
  writeB(0);
  __syncthreads();

  for (int ks = ks0; ks < ks1; ++ks) {
    const int nxt = cur ^ 1;
    const bool more = (ks + 1 < ks1);
    if (more) { stageA(ks + 1, nxt); loadB(ks + 1); }
#pragma unroll
    for (int tap = 0; tap < TAPS; ++tap) {
      sh8 af[4], bfr[NF];
#pragma unroll
      for (int m = 0; m < 4; ++m)
        af[m] = *(const sh8*)&Aw[cur][(tap * 8 + wm * 4 + m) * 512 + lane * 8];
#pragma unroll
      for (int n = 0; n < NF; ++n)
        bfr[n] = *(const sh8*)&Bx[cur][(wn * (NF * 16) + n * 16 + l15 + tap) * PB + lhi * 8];
#pragma unroll
      for (int m = 0; m < 4; ++m)
#pragma unroll
        for (int n = 0; n < NF; ++n)
          acc[m][n] = __builtin_amdgcn_mfma_f32_16x16x32_bf16(
              af[m], bfr[n], acc[m][n], 0, 0, 0);
    }
    if (more) writeB(nxt);
    __syncthreads();
    cur = nxt;
  }

  void* obase = plane == 0 ? o0p : (plane == 1 ? o1p : o2p);
  unsigned short* oph = (unsigned short*)obase + (size_t)b * T * O;
  unsigned short* opk = (unsigned short*)obase + (size_t)b * (O >> 5) * T * 32;
  unsigned short* opp = (unsigned short*)obase + ((size_t)kk * B + b) * (size_t)T * O;
#pragma unroll
  for (int m = 0; m < 4; ++m) {
    const int o = o0 + (wm * 4 + m) * 16 + (lhi << 2);
#pragma unroll
    for (int n = 0; n < NF; ++n) {
      const int t = t0 + wn * (NF * 16) + n * 16 + l15;
      const float mk = MASK_OUT ? mask[bmask + t] : 1.f;
      float v[4];
#pragma unroll
      for (int r4 = 0; r4 < 4; ++r4) {
        float x = acc[m][n][r4];
        if (KSPLIT > 1) {
          if (kk == 0) x += bp[o + r4];
        } else {
          x += bp[o + r4];
        }
        if (GELU) x = gelu_exact(x);
        if (MASK_OUT) x *= mk;
        v[r4] = x;
      }
      ushort4 hz;
      hz.x = f2b(v[0]); hz.y = f2b(v[1]); hz.z = f2b(v[2]); hz.w = f2b(v[3]);
      if constexpr (OBF16) {
        if constexpr (KBOUT)
          *(ushort4*)(opk + ((size_t)(o >> 5) * T + t) * 32 + (o & 31)) = hz;
        else
          *(ushort4*)(oph + (size_t)t * O + o) = hz;
      } else {
        // bf16 split-K partial (summed in fp32 by add_norm)
        *(ushort4*)(opp + (size_t)t * O + o) = hz;
      }
    }
  }
}

// ---------------------------------------------------------------------------
// Fused attention with 2-phase K/V prefetch. q/k/v t-major bf16 [B][T][C];
// output K-blocked bf16 [B][C/32][T][32].
__global__ __launch_bounds__(256) void fused_attn(
    const unsigned short* __restrict__ qg,
    const unsigned short* __restrict__ kg,
    const unsigned short* __restrict__ vg,
    const float* __restrict__ mask,
    const float* __restrict__ ek,
    const float* __restrict__ ev,
    unsigned short* __restrict__ outp)
{
  constexpr int PITCH = 72;
  __shared__ unsigned short Qs[64 * PITCH];
  __shared__ unsigned short Ks[2][64 * PITCH];
  __shared__ unsigned short Vs[2][64 * PITCH];
  __shared__ unsigned short Ps[64 * PITCH];
  __shared__ float eks[D * 9], evs[D * 9];
  __shared__ float qekl[64 * 12];
  __shared__ float mks[2][64];

  const int t0 = blockIdx.x * 64;
  const int bh = blockIdx.y;
  const int b = bh / H, h = bh % H;
  const int tid = threadIdx.x;
  const int lane = tid & 63, w = tid >> 6;
  const int l15 = lane & 15, lhi = lane >> 4;

  const size_t base = (size_t)b * T * C + h * D;
  const unsigned short* qh = qg + base;
  const unsigned short* kh = kg + base;
  const unsigned short* vh = vg + base;

  for (int e = tid; e < D * 9; e += 256) { eks[e] = ek[e]; evs[e] = ev[e]; }
  {
    const int tl = tid & 63, d0 = (tid >> 6) << 4;
    const unsigned short* src = qh + (size_t)(t0 + tl) * C + d0;
    *(sh8*)&Qs[tl * PITCH + d0]     = *(const sh8*)(src);
    *(sh8*)&Qs[tl * PITCH + d0 + 8] = *(const sh8*)(src + 8);
  }
  __syncthreads();
  {
    const int tl = tid & 63, g = tid >> 6;
    for (int j = g; j < 9; j += 4) {
      float a = 0.f;
      for (int d = 0; d < D; ++d)
        a = fmaf(b2f(Qs[tl * PITCH + d]), eks[d * 9 + j], a);
      qekl[tl * 12 + j] = a * 0.125f;
    }
  }
  const int t_loc = w * 16 + l15;
  const int t = t0 + t_loc;
  const float mask_t = mask[b * T + t];
  const sh8 bq0 = *(const sh8*)&Qs[t_loc * PITCH + lhi * 8];
  const sh8 bq1 = *(const sh8*)&Qs[t_loc * PITCH + 32 + lhi * 8];

  const int sl = tid & 63, d0s = (tid >> 6) << 4;
  {
    const unsigned short* srck = kh + (size_t)sl * C + d0s;
    *(sh8*)&Ks[0][sl * PITCH + d0s]     = *(const sh8*)(srck);
    *(sh8*)&Ks[0][sl * PITCH + d0s + 8] = *(const sh8*)(srck + 8);
    const unsigned short* srcv = vh + (size_t)sl * C + d0s;
    sh8 u0 = *(const sh8*)(srcv);
    sh8 u1 = *(const sh8*)(srcv + 8);
#pragma unroll
    for (int j = 0; j < 8; ++j) Vs[0][(d0s + j) * PITCH + sl] = (unsigned short)u0[j];
#pragma unroll
    for (int j = 0; j < 8; ++j) Vs[0][(d0s + 8 + j) * PITCH + sl] = (unsigned short)u1[j];
    if (tid < 64) mks[0][tid] = mask[b * T + tid];
  }
  __syncthreads();

  float m_run = -1e30f, l_run = 0.f;
  f32x4 oacc[4] = {};
  int cur = 0;
  sh8 kr0, kr1, vr0, vr1;
  float mkr = 0.f;

  for (int s0 = 0; s0 < T; s0 += 64) {
    const int nxt = cur ^ 1;
    const bool more = (s0 + 64 < T);
    if (more) {
      const unsigned short* srck = kh + (size_t)(s0 + 64 + sl) * C + d0s;
      kr0 = *(const sh8*)(srck);
      kr1 = *(const sh8*)(srck + 8);
      const unsigned short* srcv = vh + (size_t)(s0 + 64 + sl) * C + d0s;
      vr0 = *(const sh8*)(srcv);
      vr1 = *(const sh8*)(srcv + 8);
      if (tid < 64) mkr = mask[b * T + s0 + 64 + tid];
    }

    float p[16];
#pragma unroll
    for (int n = 0; n < 4; ++n) {
      const sh8 a0 = *(const sh8*)&Ks[cur][(n * 16 + l15) * PITCH + lhi * 8];
      const sh8 a1 = *(const sh8*)&Ks[cur][(n * 16 + l15) * PITCH + 32 + lhi * 8];
      f32x4 acc = {};
      __builtin_amdgcn_s_setprio(1);
      acc = __builtin_amdgcn_mfma_f32_16x16x32_bf16(a0, bq0, acc, 0, 0, 0);
      acc = __builtin_amdgcn_mfma_f32_16x16x32_bf16(a1, bq1, acc, 0, 0, 0);
      __builtin_amdgcn_s_setprio(0);
#pragma unroll
      for (int r = 0; r < 4; ++r) {
        const int s = s0 + n * 16 + lhi * 4 + r;
        float v = acc[r] * 0.125f;
        const int j = s - t + 4;
        if ((unsigned)j < 9u) v += qekl[t_loc * 12 + j];
        if (mask_t * mks[cur][s - s0] == 0.f) v = -10000.0f;
        p[n * 4 + r] = v;
      }
    }
    float mloc = p[0];
#pragma unroll
    for (int i = 1; i < 16; ++i) mloc = fmaxf(mloc, p[i]);
    mloc = fmaxf(mloc, __shfl_xor(mloc, 16));
    mloc = fmaxf(mloc, __shfl_xor(mloc, 32));
    const float m_new = fmaxf(m_run, mloc);
    const float f = __expf(m_run - m_new);
    float sloc = 0.f;
#pragma unroll
    for (int i = 0; i < 16; ++i) { p[i] = __expf(p[i] - m_new); sloc += p[i]; }
    sloc += __shfl_xor(sloc, 16);
    sloc += __shfl_xor(sloc, 32);
    l_run = l_run * f + sloc;
    m_run = m_new;
#pragma unroll
    for (int m = 0; m < 4; ++m)
#pragma unroll
      for (int r = 0; r < 4; ++r) oacc[m][r] *= f;
#pragma unroll
    for (int n = 0; n < 4; ++n) {
      uint2 pk;
      pk.x = (unsigned)f2b(p[n * 4 + 0]) | ((unsigned)f2b(p[n * 4 + 1]) << 16);
      pk.y = (unsigned)f2b(p[n * 4 + 2]) | ((unsigned)f2b(p[n * 4 + 3]) << 16);
      *(uint2*)&Ps[t_loc * PITCH + n * 16 + lhi * 4] = pk;
    }
    asm volatile("s_waitcnt lgkmcnt(0)" ::: "memory");
    const sh8 bp0 = *(const sh8*)&Ps[t_loc * PITCH + lhi * 8];
    const sh8 bp1 = *(const sh8*)&Ps[t_loc * PITCH + 32 + lhi * 8];
    __builtin_amdgcn_s_setprio(1);
#pragma unroll
    for (int m = 0; m < 4; ++m) {
      const sh8 a0 = *(const sh8*)&Vs[cur][(m * 16 + l15) * PITCH + lhi * 8];
      const sh8 a1 = *(const sh8*)&Vs[cur][(m * 16 + l15) * PITCH + 32 + lhi * 8];
      oacc[m] = __builtin_amdgcn_mfma_f32_16x16x32_bf16(a0, bp0, oacc[m], 0, 0, 0);
      oacc[m] = __builtin_amdgcn_mfma_f32_16x16x32_bf16(a1, bp1, oacc[m], 0, 0, 0);
    }
    __builtin_amdgcn_s_setprio(0);
    if (t + 4 >= s0 && t < s0 + 68) {
#pragma unroll
      for (int j = 0; j < 9; ++j) {
        const int s = t + j - 4;
        if (s >= s0 && s < s0 + 64) {
          const float pv = b2f(Ps[t_loc * PITCH + (s - s0)]);
#pragma unroll
          for (int m = 0; m < 4; ++m)
#pragma unroll
            for (int r = 0; r < 4; ++r)
              oacc[m][r] = fmaf(pv, evs[(m * 16 + lhi * 4 + r) * 9 + j], oacc[m][r]);
        }
      }
    }
    if (more) {
      *(sh8*)&Ks[nxt][sl * PITCH + d0s]     = kr0;
      *(sh8*)&Ks[nxt][sl * PITCH + d0s + 8] = kr1;
#pragma unroll
      for (int j = 0; j < 8; ++j) Vs[nxt][(d0s + j) * PITCH + sl] = (unsigned short)vr0[j];
#pragma unroll
      for (int j = 0; j < 8; ++j) Vs[nxt][(d0s + 8 + j) * PITCH + sl] = (unsigned short)vr1[j];
      if (tid < 64) mks[nxt][tid] = mkr;
    }
    __syncthreads();
    cur = nxt;
  }
  const float invl = 1.f / l_run;
  unsigned short* okb = outp + (size_t)b * (C >> 5) * T * 32;
#pragma unroll
  for (int m = 0; m < 4; ++m) {
    ushort4 hz;
    hz.x = f2b(oacc[m][0] * invl);
    hz.y = f2b(oacc[m][1] * invl);
    hz.z = f2b(oacc[m][2] * invl);
    hz.w = f2b(oacc[m][3] * invl);
    const int c = h * D + m * 16 + lhi * 4;
    *(ushort4*)(okb + ((size_t)(c >> 5) * T + t) * 32 + (c & 31)) = hz;
  }
}

// ---------------------------------------------------------------------------
// Wave-per-t add+layernorm; y partials now BF16 [NP][B][T][C] (fp32 sum here).
template <int NP, bool MASKY, bool MASKF>
__global__ __launch_bounds__(256) void add_norm_wave(
    const float* __restrict__ xr, const unsigned short* __restrict__ ypart,
    const float* __restrict__ g, const float* __restrict__ bta,
    const float* __restrict__ mask, float* __restrict__ dst,
    unsigned short* __restrict__ dsth)
{
  const int b = blockIdx.y;
  const int t = blockIdx.x * 4 + (threadIdx.x >> 6);
  const int lane = threadIdx.x & 63;
  const float mkt = mask[b * T + t];
  const size_t rowoff = ((size_t)b * T + t) * C;
  const int ci0 = lane * 12;

  float vv[12];
  float sum = 0.f, sq = 0.f;
#pragma unroll
  for (int q = 0; q < 3; ++q) {
    const int ci = ci0 + q * 4;
    float4 xv = *(const float4*)(xr + rowoff + ci);
    float y0 = 0.f, y1 = 0.f, y2 = 0.f, y3 = 0.f;
#pragma unroll
    for (int p = 0; p < NP; ++p) {
      const unsigned short* pp =
          ypart + ((size_t)p * B * T + (size_t)b * T + t) * C + ci;
      uint2 u = *(const uint2*)pp;   // 4 bf16, 8B-aligned
      y0 += b2f((unsigned short)(u.x & 0xffffu));
      y1 += b2f((unsigned short)(u.x >> 16));
      y2 += b2f((unsigned short)(u.y & 0xffffu));
      y3 += b2f((unsigned short)(u.y >> 16));
    }
    if (MASKY) { y0 *= mkt; y1 *= mkt; y2 *= mkt; y3 *= mkt; }
    const float v0 = xv.x + y0, v1 = xv.y + y1;
    const float v2 = xv.z + y2, v3 = xv.w + y3;
    vv[q * 4 + 0] = v0; vv[q * 4 + 1] = v1; vv[q * 4 + 2] = v2; vv[q * 4 + 3] = v3;
    sum += v0 + v1 + v2 + v3;
    sq = fmaf(v0, v0, fmaf(v1, v1, fmaf(v2, v2, fmaf(v3, v3, sq))));
  }
#pragma unroll
  for (int o = 32; o > 0; o >>= 1) {
    sum += __shfl_xor(sum, o);
    sq += __shfl_xor(sq, o);
  }
  const float m = sum * (1.f / C);
  const float rs = rsqrtf(sq * (1.f / C) - m * m + 1e-5f);
#pragma unroll
  for (int q = 0; q < 3; ++q) {
    const int ci = ci0 + q * 4;
    float4 gv = *(const float4*)(g + ci);
    float4 bv = *(const float4*)(bta + ci);
    float o0 = (vv[q * 4 + 0] - m) * rs * gv.x + bv.x;
    float o1 = (vv[q * 4 + 1] - m) * rs * gv.y + bv.y;
    float o2 = (vv[q * 4 + 2] - m) * rs * gv.z + bv.z;
    float o3 = (vv[q * 4 + 3] - m) * rs * gv.w + bv.w;
    if (MASKF) { o0 *= mkt; o1 *= mkt; o2 *= mkt; o3 *= mkt; }
    *(float4*)(dst + rowoff + ci) = make_float4(o0, o1, o2, o3);
    const float hm = MASKF ? 1.f : mkt;
    ushort4 hz;
    hz.x = f2b(o0 * hm); hz.y = f2b(o1 * hm); hz.z = f2b(o2 * hm); hz.w = f2b(o3 * hm);
    *(ushort4*)(dsth + rowoff + ci) = hz;
  }
}

}  // namespace

extern "C" void kernel_launch(void* const* d_in, const int* in_sizes, int n_in,
                              void* d_out, int out_size, void* d_ws, size_t ws_size,
                              hipStream_t stream) {
  const float* x_in = (const float*)d_in[0];
  const float* mask = (const float*)d_in[1];
  const float* Wq = (const float*)d_in[2];
  const float* bq = (const float*)d_in[3];
  const float* Wk = (const float*)d_in[4];
  const float* bk = (const float*)d_in[5];
  const float* Wv = (const float*)d_in[6];
  const float* bv = (const float*)d_in[7];
  const float* Wo = (const float*)d_in[8];
  const float* bo = (const float*)d_in[9];
  const float* ek = (const float*)d_in[10];
  const float* ev = (const float*)d_in[11];
  const float* w1 = (const float*)d_in[12];
  const float* b1 = (const float*)d_in[13];
  const float* w2 = (const float*)d_in[14];
  const float* b2 = (const float*)d_in[15];
  const float* n1g = (const float*)d_in[16];
  const float* n1b = (const float*)d_in[17];
  const float* n2g = (const float*)d_in[18];
  const float* n2b = (const float*)d_in[19];

  float* ws = (float*)d_ws;
  const size_t SZ_X = (size_t)B * C * T;
  const size_t SZ_W1 = (size_t)3 * FF * C;
  float* xr    = ws;
  float* xr1   = xr + SZ_X;
  unsigned short* yparth = (unsigned short*)(xr1 + SZ_X);  // [4][B][T][C] bf16
  unsigned short* xbh = yparth + 4 * SZ_X;
  unsigned short* xfh = xbh + SZ_X;
  unsigned short* qbh = xfh + SZ_X;
  unsigned short* kbh = qbh + SZ_X;
  unsigned short* vbh = kbh + SZ_X;
  unsigned short* hidh = vbh + SZ_X;
  unsigned short* w1t = hidh + (size_t)B * FF * T;
  unsigned short* w2t = w1t + (size_t)NL * SZ_W1;
  unsigned short* wqt = w2t + (size_t)NL * SZ_W1;
  unsigned short* wkt = wqt + (size_t)NL * C * C;
  unsigned short* wvt = wkt + (size_t)NL * C * C;
  unsigned short* wot = wvt + (size_t)NL * C * C;
  float* outp = (float*)d_out;

  const dim3 blk(256);
  transpose_cvt_in<<<dim3(T / 32, C / 32, B), blk, 0, stream>>>(x_in, xbh, xr);
  cvt_qkvo_tiled<<<dim3((C / 16) * (C / 128), 4, NL), blk, 0, stream>>>(
      Wq, Wk, Wv, Wo, wqt, wkt, wvt, wot);
  cvt_ffn_tiled<<<dim3((FF / 16) * (C / 128), 2, NL), blk, 0, stream>>>(
      w1, w2, w1t, w2t);

  for (int i = 0; i < NL; ++i) {
    const size_t wOff = (size_t)i * C * C;
    const unsigned short* w1l = w1t + (size_t)i * SZ_W1;
    const unsigned short* w2l = w2t + (size_t)i * SZ_W1;
    // QKV projection -> bf16 q,k,v t-major   (576 blocks, BN=64)
    mfma_conv<1, 64, 1, false, false, true, false, false>
        <<<dim3(8 * 18 * 4), blk, 0, stream>>>(
        xbh, wqt + wOff, wkt + wOff, wvt + wOff,
        bq + i * C, bk + i * C, bv + i * C, mask,
        qbh, kbh, vbh, C, C, 6, 4);
    // fused attention -> K-blocked bf16
    fused_attn<<<dim3(T / 64, B * H), blk, 0, stream>>>(
        qbh, kbh, vbh, mask, ek + (size_t)i * D * 9, ev + (size_t)i * D * 9, hidh);
    // Wo projection: K-blocked input, split-K3 -> bf16 partials (576 blocks)
    mfma_conv<1, 64, 3, false, false, false, true, false>
        <<<dim3(8 * 6 * 12), blk, 0, stream>>>(
        hidh, wot + wOff, wot + wOff, wot + wOff,
        bo + i * C, bo + i * C, bo + i * C, mask,
        yparth, yparth, yparth, C, C, 6, 12);
    add_norm_wave<3, false, false><<<dim3(T / 4, B), blk, 0, stream>>>(
        xr, yparth, n1g + i * C, n1b + i * C, mask, xr1, xfh);
    // FFN up: t-major in, GELU+mask, K-blocked bf16 out   (384 blocks)
    mfma_conv<3, 128, 1, true, true, true, false, true>
        <<<dim3(4 * 24 * 4), blk, 0, stream>>>(
        xfh, w1l, w1l, w1l, b1 + i * FF, b1 + i * FF, b1 + i * FF, mask,
        hidh, hidh, hidh, C, FF, 24, 4);
    // FFN down: K-blocked in, split-K4 -> bf16 partials   (384 blocks)
    mfma_conv<3, 128, 4, false, false, false, true, false>
        <<<dim3(4 * 6 * 16), blk, 0, stream>>>(
        hidh, w2l, w2l, w2l, b2 + i * C, b2 + i * C, b2 + i * C, mask,
        yparth, yparth, yparth, FF, C, 6, 16);
    add_norm_wave<4, true, true><<<dim3(T / 4, B), blk, 0, stream>>>(
        xr1, yparth, n2g + i * C, n2b + i * C, mask, xr, xbh);
  }
  transpose_out<<<dim3(T / 32, C / 32, B), blk, 0, stream>>>(xr, outp);
}